// Round 2
// baseline (246.938 us; speedup 1.0000x reference)
//
#include <hip/hip_runtime.h>
#include <math.h>

#define BB 2
#define SEQ 2048
#define DMODEL 1024
#define NHH 16
#define DHH 64

typedef __bf16 bf16;
typedef __attribute__((ext_vector_type(8))) __bf16 bf16x8;
typedef __attribute__((ext_vector_type(4))) float f32x4;
typedef __attribute__((ext_vector_type(16))) float f32x16;

// p = exp2(s*C1 + C2) = exp(0.125*s - 4)   [static-max softmax, 0.125*|s| <~ 2.5]
#define C1f 0.18033688011112042f
#define C2f -5.770780163555854f

__device__ __forceinline__ uint32_t cvtpk_bf16(float lo, float hi) {
  uint32_t r;
  asm("v_cvt_pk_bf16_f32 %0, %1, %2" : "=v"(r) : "v"(lo), "v"(hi));
  return r;
}
__device__ __forceinline__ void pl32swap(uint32_t& a, uint32_t& b) {
  asm("v_permlane32_swap_b32 %0, %1" : "+v"(a), "+v"(b));
}

// ---------------------------------------------------------------------------
// fp32 -> bf16 convert for both activations in one launch (blockIdx.y picks)
// ---------------------------------------------------------------------------
__global__ __launch_bounds__(256) void cvt2_bf16(const float* __restrict__ in0,
                                                 bf16* __restrict__ out0,
                                                 const float* __restrict__ in1,
                                                 bf16* __restrict__ out1, int n8) {
  int i = blockIdx.x * 256 + threadIdx.x;
  if (i >= n8) return;
  const float* in = blockIdx.y ? in1 : in0;
  bf16* out = blockIdx.y ? out1 : out0;
  const float4* p = (const float4*)in + 2 * (size_t)i;
  float4 a = p[0], b = p[1];
  bf16x8 v;
  v[0] = (bf16)a.x; v[1] = (bf16)a.y; v[2] = (bf16)a.z; v[3] = (bf16)a.w;
  v[4] = (bf16)b.x; v[5] = (bf16)b.y; v[6] = (bf16)b.z; v[7] = (bf16)b.w;
  *((bf16x8*)out + i) = v;
}

// ---------------------------------------------------------------------------
// Weight transpose+convert via LDS tile: Wt[n][k] = (bf16) W[k][n].
// ---------------------------------------------------------------------------
__global__ __launch_bounds__(256) void wt_cvt(const float* __restrict__ W0, const float* __restrict__ W1,
                                              const float* __restrict__ W2, const float* __restrict__ W3,
                                              bf16* __restrict__ O0, bf16* __restrict__ O1,
                                              bf16* __restrict__ O2, bf16* __restrict__ O3) {
  __shared__ bf16 T[64][72];
  const float* W; bf16* O;
  switch (blockIdx.z) {
    case 0: W = W0; O = O0; break;
    case 1: W = W1; O = O1; break;
    case 2: W = W2; O = O2; break;
    default: W = W3; O = O3; break;
  }
  const int n0 = blockIdx.x * 64, k0 = blockIdx.y * 64;
  const int t = threadIdx.x;
  {
    int k = t >> 2, ns = (t & 3) * 16;
    const float* g = W + (size_t)(k0 + k) * DMODEL + n0 + ns;
#pragma unroll
    for (int q = 0; q < 4; ++q) {
      float4 f = *(const float4*)(g + 4 * q);
      T[ns + 4 * q + 0][k] = (bf16)f.x;
      T[ns + 4 * q + 1][k] = (bf16)f.y;
      T[ns + 4 * q + 2][k] = (bf16)f.z;
      T[ns + 4 * q + 3][k] = (bf16)f.w;
    }
  }
  __syncthreads();
  {
    int n = t >> 2, ks = (t & 3) * 16;
    bf16x8 a = *(const bf16x8*)&T[n][ks];
    bf16x8 b = *(const bf16x8*)&T[n][ks + 8];
    bf16* o = O + (size_t)(n0 + n) * DMODEL + k0 + ks;
    *(bf16x8*)o = a;
    *(bf16x8*)(o + 8) = b;
  }
}

// ---------------------------------------------------------------------------
// bf16 MFMA GEMM, 64(m) x 128(n) tile, BK=64, DEPTH-2 register-prefetch,
// XOR-swizzled unpadded LDS. 4 waves in 2x2; wave = 32x64 (2x4 frags).
// ---------------------------------------------------------------------------
template <bool F32OUT>
__device__ __forceinline__ void gemm64_body(const bf16* __restrict__ A,
                                            const bf16* __restrict__ Bt,
                                            float* __restrict__ Cf,
                                            bf16* __restrict__ Cb,
                                            bf16* As, bf16* Bs) {
  const int t = threadIdx.x;
  const int lane = t & 63, wave = t >> 6;
  const int l15 = lane & 15, quad = lane >> 4;
  const int bm = blockIdx.y * 64, bn = blockIdx.x * 128;
  const int wr = wave >> 1, wc = wave & 1;

  const int srow = t >> 3;
  const int slot = t & 7;
  const int schunk = slot ^ (srow & 7);
  const bf16* gA = A + (size_t)(bm + srow) * DMODEL + schunk * 8;
  const bf16* gB = Bt + (size_t)(bn + srow) * DMODEL + schunk * 8;
  const int soff = srow * 64 + slot * 8;

  bf16x8 areg[2][2], breg[2][4];
#pragma unroll
  for (int s = 0; s < 2; ++s) {
#pragma unroll
    for (int j = 0; j < 2; ++j)
      areg[s][j] = *(const bf16x8*)(gA + (size_t)(32 * j) * DMODEL + s * 64);
#pragma unroll
    for (int j = 0; j < 4; ++j)
      breg[s][j] = *(const bf16x8*)(gB + (size_t)(32 * j) * DMODEL + s * 64);
  }

  f32x4 acc[2][4] = {};

#pragma unroll
  for (int it = 0; it < 16; ++it) {
    const int sel = it & 1;
    __syncthreads();  // prev frag reads done
#pragma unroll
    for (int j = 0; j < 2; ++j) *(bf16x8*)&As[j * 2048 + soff] = areg[sel][j];
#pragma unroll
    for (int j = 0; j < 4; ++j) *(bf16x8*)&Bs[j * 2048 + soff] = breg[sel][j];
    __syncthreads();
    if (it + 2 < 16) {
      const int kn = (it + 2) * 64;
#pragma unroll
      for (int j = 0; j < 2; ++j)
        areg[sel][j] = *(const bf16x8*)(gA + (size_t)(32 * j) * DMODEL + kn);
#pragma unroll
      for (int j = 0; j < 4; ++j)
        breg[sel][j] = *(const bf16x8*)(gB + (size_t)(32 * j) * DMODEL + kn);
    }
#pragma unroll
    for (int ks = 0; ks < 2; ++ks) {
      bf16x8 af[2], bfr[4];
#pragma unroll
      for (int mt = 0; mt < 2; ++mt) {
        int row = wr * 32 + mt * 16 + l15;
        int s = (ks * 4 + quad) ^ (row & 7);
        af[mt] = *(const bf16x8*)&As[row * 64 + s * 8];
      }
#pragma unroll
      for (int nt = 0; nt < 4; ++nt) {
        int row = wc * 64 + nt * 16 + l15;
        int s = (ks * 4 + quad) ^ (row & 7);
        bfr[nt] = *(const bf16x8*)&Bs[row * 64 + s * 8];
      }
#pragma unroll
      for (int mt = 0; mt < 2; ++mt)
#pragma unroll
        for (int nt = 0; nt < 4; ++nt)
          acc[mt][nt] = __builtin_amdgcn_mfma_f32_16x16x32_bf16(af[mt], bfr[nt], acc[mt][nt], 0, 0, 0);
    }
  }

#pragma unroll
  for (int mt = 0; mt < 2; ++mt)
#pragma unroll
    for (int nt = 0; nt < 4; ++nt)
#pragma unroll
      for (int r = 0; r < 4; ++r) {
        int row = bm + wr * 32 + mt * 16 + quad * 4 + r;
        int col = bn + wc * 64 + nt * 16 + l15;
        if (F32OUT) Cf[(size_t)row * DMODEL + col] = acc[mt][nt][r];
        else Cb[(size_t)row * DMODEL + col] = (bf16)acc[mt][nt][r];
      }
}

__global__ __launch_bounds__(256) void gemm_qkv(const bf16* __restrict__ qbf,
                                                const bf16* __restrict__ kvbf,
                                                const bf16* __restrict__ WtQ,
                                                const bf16* __restrict__ WtK,
                                                const bf16* __restrict__ WtV,
                                                bf16* __restrict__ Qb,
                                                bf16* __restrict__ Kb,
                                                bf16* __restrict__ Vb) {
  __shared__ bf16 As[64 * 64];
  __shared__ bf16 Bs[128 * 64];
  const bf16 *A, *Bt; bf16* C;
  switch (blockIdx.z) {
    case 0: A = qbf; Bt = WtQ; C = Qb; break;
    case 1: A = kvbf; Bt = WtK; C = Kb; break;
    default: A = kvbf; Bt = WtV; C = Vb; break;
  }
  gemm64_body<false>(A, Bt, nullptr, C, As, Bs);
}

__global__ __launch_bounds__(256) void gemm_out(const bf16* __restrict__ A,
                                                const bf16* __restrict__ Wt,
                                                float* __restrict__ C) {
  __shared__ bf16 As[64 * 64];
  __shared__ bf16 Bs[128 * 64];
  gemm64_body<true>(A, Wt, C, nullptr, As, Bs);
}

// ---------------------------------------------------------------------------
// MFMA flash attention, LDS-issue-minimized version:
//  * 32x32x16 MFMAs, swapped operands: S^T = K(A) . Q^T(B)  -> lane holds
//    P[q=l31][k=crow(r,hi)+32kt] in registers (crow = (r&3)+8*(r>>2)+4*hi).
//  * P -> bf16 PV B-fragments fully in-register: v_cvt_pk_bf16_f32 +
//    v_permlane32_swap_b32 (no Ps LDS round-trip).
//  * K fragments read global->reg (L1/L2-resident, wave-shared data);
//    only V goes through LDS (needs the [d][n] transpose). LDS 17.4 KB.
//  * mask as per-chunk 64-bit __ballot bitmask, applied to P in registers;
//    softmax denom l = lane-local VALU sum + shfl_xor(32) at the end.
//  * PV: O^T = V^T(A) . P^T(B); epilogue stores packed 8B per r-group.
// Block = (b,h,128 Q rows), 4 waves x 32 q-rows. Grid 512 (2 blocks/CU).
// ---------------------------------------------------------------------------
__global__ __launch_bounds__(256, 2) void attn_mfma(const bf16* __restrict__ Qb,
                                                    const bf16* __restrict__ Kb,
                                                    const bf16* __restrict__ Vb,
                                                    const int* __restrict__ maskp,
                                                    bf16* __restrict__ Ob) {
  __shared__ bf16 Vt[2][64][68];  // [d][n], double-buffered (17.4 KB)

  const int blk = blockIdx.x;
  const int h = blk & 15;
  const int b = (blk >> 4) & 1;
  const int qb = blk >> 5;  // 0..15, 128-row Q tile
  const int t = threadIdx.x;
  const int wave = t >> 6, lane = t & 63;
  const int l31 = lane & 31, hi = lane >> 5;

  // V staging map: tokens nv,nv+1 x 8 d per thread
  const int nv = (t & 31) * 2, dc = (t >> 5) * 8;
  const bf16* gV = Vb + (size_t)(b * SEQ + nv) * DMODEL + h * 64 + dc;
  const int* gM = maskp + b * SEQ;

  // ---- stage chunk 0 V into buffer 0 (no mask: P is masked in-register) ----
  {
    bf16x8 v0 = *(const bf16x8*)(gV);
    bf16x8 v1 = *(const bf16x8*)(gV + DMODEL);
    union U { bf16x8 v; uint32_t dw[4]; } a, c;
    a.v = v0; c.v = v1;
#pragma unroll
    for (int d2 = 0; d2 < 4; ++d2) {
      *(uint32_t*)&Vt[0][dc + 2 * d2 + 0][nv] = __builtin_amdgcn_perm(c.dw[d2], a.dw[d2], 0x05040100u);
      *(uint32_t*)&Vt[0][dc + 2 * d2 + 1][nv] = __builtin_amdgcn_perm(c.dw[d2], a.dw[d2], 0x07060302u);
    }
  }

  // mask preload for chunk 0 (every wave: lane = token index)
  int mcur = gM[lane];

  // Q as B-operand fragments: lane holds Q[q=l31][d = ks*16 + hi*8 + j]
  bf16x8 qf[4];
#pragma unroll
  for (int ks = 0; ks < 4; ++ks) {
    const bf16* g = Qb + (size_t)(b * SEQ + qb * 128 + wave * 32 + l31) * DMODEL +
                    h * 64 + ks * 16 + hi * 8;
    qf[ks] = *(const bf16x8*)g;
  }

  // K lane base: A-operand frag row = k-token = it*64 + kt*32 + l31
  const bf16* gK0 = Kb + (size_t)(b * SEQ + l31) * DMODEL + h * 64 + hi * 8;

  f32x16 o0 = {}, o1 = {};
  float lsum = 0.f;

  __syncthreads();  // buffer 0 ready

  for (int it = 0; it < SEQ / 64; ++it) {
    const int p = it & 1;
    const bool more = (it + 1) < SEQ / 64;

    // ---- K fragments for THIS chunk: issue first (counted vmcnt lets the
    //      V prefetch below stay in flight through the MFMAs) ----
    const bf16* gKit = gK0 + (size_t)(it * 64) * DMODEL;
    bf16x8 ka0[4], ka1[4];
#pragma unroll
    for (int ks = 0; ks < 4; ++ks) {
      ka0[ks] = *(const bf16x8*)(gKit + ks * 16);
      ka1[ks] = *(const bf16x8*)(gKit + (size_t)32 * DMODEL + ks * 16);
    }

    // ---- issue next-chunk V/mask loads (LDS-written at the bottom) ----
    bf16x8 vreg0, vreg1;
    int mnext = 0;
    if (more) {
      const int nn = (it + 1) * 64;
      const bf16* gV2 = gV + (size_t)nn * DMODEL;
      vreg0 = *(const bf16x8*)(gV2);
      vreg1 = *(const bf16x8*)(gV2 + DMODEL);
      mnext = gM[nn + lane];
    }

    // ---- S^T = K . Q^T : s[kt][r] = S[q=l31][k = kt*32 + crow(r,hi)] ----
    f32x16 s0 = {}, s1 = {};
#pragma unroll
    for (int ks = 0; ks < 4; ++ks) {
      s0 = __builtin_amdgcn_mfma_f32_32x32x16_bf16(ka0[ks], qf[ks], s0, 0, 0, 0);
      s1 = __builtin_amdgcn_mfma_f32_32x32x16_bf16(ka1[ks], qf[ks], s1, 0, 0, 0);
    }

    // ---- mask bitmask for this chunk (bit k = 1 means keep) ----
    const unsigned long long mb = __ballot(mcur == 0);

    // ---- exp + mask + l-sum + in-register P->bf16 B-frags + PV ----
#pragma unroll
    for (int kt = 0; kt < 2; ++kt) {
      const f32x16 sv = kt ? s1 : s0;
      const uint32_t ml = (uint32_t)(mb >> (kt * 32 + 4 * hi));
      float pm[16];
#pragma unroll
      for (int r = 0; r < 16; ++r) {
        const int bitc = (r & 3) + 8 * (r >> 2);
        float pex = __builtin_amdgcn_exp2f(sv[r] * C1f + C2f);
        pm[r] = ((ml >> bitc) & 1u) ? pex : 0.f;
        lsum += pm[r];
      }
      // pack pairs (ascending k within lane)
      uint32_t w01 = cvtpk_bf16(pm[0], pm[1]),  w23 = cvtpk_bf16(pm[2], pm[3]);
      uint32_t w45 = cvtpk_bf16(pm[4], pm[5]),  w67 = cvtpk_bf16(pm[6], pm[7]);
      uint32_t w89 = cvtpk_bf16(pm[8], pm[9]),  wab = cvtpk_bf16(pm[10], pm[11]);
      uint32_t wcd = cvtpk_bf16(pm[12], pm[13]), wef = cvtpk_bf16(pm[14], pm[15]);
      // lane-half exchange: after swap, {w01,w23,w45,w67} = B-frag k=kt*32+0..15,
      // {w89,wab,wcd,wef} = B-frag k=kt*32+16..31 (all lanes correct).
      pl32swap(w01, w45);
      pl32swap(w23, w67);
      pl32swap(w89, wcd);
      pl32swap(wab, wef);
      union BF { uint32_t u[4]; bf16x8 v; } f0, f1;
      f0.u[0] = w01; f0.u[1] = w23; f0.u[2] = w45; f0.u[3] = w67;
      f1.u[0] = w89; f1.u[1] = wab; f1.u[2] = wcd; f1.u[3] = wef;
      // PV: O^T += V^T(A) . P^T(B); V^T frag = Vt[d = dt*32+l31][k + hi*8]
      {
        bf16x8 va00 = *(const bf16x8*)&Vt[p][0 + l31][(kt * 2 + 0) * 16 + hi * 8];
        bf16x8 va01 = *(const bf16x8*)&Vt[p][0 + l31][(kt * 2 + 1) * 16 + hi * 8];
        o0 = __builtin_amdgcn_mfma_f32_32x32x16_bf16(va00, f0.v, o0, 0, 0, 0);
        o0 = __builtin_amdgcn_mfma_f32_32x32x16_bf16(va01, f1.v, o0, 0, 0, 0);
        bf16x8 va10 = *(const bf16x8*)&Vt[p][32 + l31][(kt * 2 + 0) * 16 + hi * 8];
        bf16x8 va11 = *(const bf16x8*)&Vt[p][32 + l31][(kt * 2 + 1) * 16 + hi * 8];
        o1 = __builtin_amdgcn_mfma_f32_32x32x16_bf16(va10, f0.v, o1, 0, 0, 0);
        o1 = __builtin_amdgcn_mfma_f32_32x32x16_bf16(va11, f1.v, o1, 0, 0, 0);
      }
    }

    // ---- write staged V chunk into buffer 1-p ----
    if (more) {
      const int q = 1 - p;
      union U { bf16x8 v; uint32_t dw[4]; } a, c;
      a.v = vreg0; c.v = vreg1;
#pragma unroll
      for (int d2 = 0; d2 < 4; ++d2) {
        *(uint32_t*)&Vt[q][dc + 2 * d2 + 0][nv] = __builtin_amdgcn_perm(c.dw[d2], a.dw[d2], 0x05040100u);
        *(uint32_t*)&Vt[q][dc + 2 * d2 + 1][nv] = __builtin_amdgcn_perm(c.dw[d2], a.dw[d2], 0x07060302u);
      }
    }
    mcur = mnext;
    __syncthreads();  // buffer 1-p written, buffer p reads complete
  }

  // ---- epilogue: l = own half + partner half (lane^32); normalize, store ----
  const float lt = lsum + __shfl_xor(lsum, 32);
  const float inv = 1.f / lt;
  bf16* gO = Ob + (size_t)(b * SEQ + qb * 128 + wave * 32 + l31) * DMODEL + h * 64;
#pragma unroll
  for (int g = 0; g < 4; ++g) {
    // o[r] holds d = dt*32 + 8*g + 4*hi + (r&3); pack 4 consecutive d -> 8B
    uint2 st0, st1;
    st0.x = cvtpk_bf16(o0[4 * g + 0] * inv, o0[4 * g + 1] * inv);
    st0.y = cvtpk_bf16(o0[4 * g + 2] * inv, o0[4 * g + 3] * inv);
    st1.x = cvtpk_bf16(o1[4 * g + 0] * inv, o1[4 * g + 1] * inv);
    st1.y = cvtpk_bf16(o1[4 * g + 2] * inv, o1[4 * g + 3] * inv);
    *(uint2*)(gO + 8 * g + 4 * hi) = st0;
    *(uint2*)(gO + 32 + 8 * g + 4 * hi) = st1;
  }
}

// ---------------------------------------------------------------------------
extern "C" void kernel_launch(void* const* d_in, const int* in_sizes, int n_in,
                              void* d_out, int out_size, void* d_ws, size_t ws_size,
                              hipStream_t stream) {
  (void)in_sizes; (void)n_in; (void)out_size; (void)ws_size;
  const float* query = (const float*)d_in[0];
  const float* key_value = (const float*)d_in[1];
  const int* mask = (const int*)d_in[2];
  const float* W_Q = (const float*)d_in[3];
  const float* W_K = (const float*)d_in[4];
  const float* W_V = (const float*)d_in[5];
  const float* W_O = (const float*)d_in[6];
  float* out = (float*)d_out;

  const size_t TOK = (size_t)BB * SEQ;  // 4096
  const size_t TE = TOK * DMODEL;       // 4,194,304 elems
  char* w = (char*)d_ws;
  bf16* qbf = (bf16*)w;   w += TE * 2;
  bf16* kvbf = (bf16*)w;  w += TE * 2;
  bf16* WtQ = (bf16*)w;   w += (size_t)DMODEL * DMODEL * 2;
  bf16* WtK = (bf16*)w;   w += (size_t)DMODEL * DMODEL * 2;
  bf16* WtV = (bf16*)w;   w += (size_t)DMODEL * DMODEL * 2;
  bf16* WtO = (bf16*)w;   w += (size_t)DMODEL * DMODEL * 2;
  bf16* Qbuf = (bf16*)w;  w += TE * 2;
  bf16* Kbuf = (bf16*)w;  w += TE * 2;
  bf16* Vbuf = (bf16*)w;  w += TE * 2;
  bf16* Obuf = (bf16*)w;  w += TE * 2;

  cvt2_bf16<<<dim3(TE / 8 / 256, 2), 256, 0, stream>>>(query, qbf, key_value, kvbf, TE / 8);
  wt_cvt<<<dim3(16, 16, 4), 256, 0, stream>>>(W_Q, W_K, W_V, W_O, WtQ, WtK, WtV, WtO);

  gemm_qkv<<<dim3(DMODEL / 128, TOK / 64, 3), 256, 0, stream>>>(qbf, kvbf, WtQ, WtK, WtV,
                                                                Qbuf, Kbuf, Vbuf);

  attn_mfma<<<BB * NHH * (SEQ / 128), 256, 0, stream>>>(Qbuf, Kbuf, Vbuf, mask, Obuf);

  gemm_out<<<dim3(DMODEL / 128, TOK / 64), 256, 0, stream>>>(Obuf, WtO, out);
}

// Round 3
// 240.546 us; speedup vs baseline: 1.0266x; 1.0266x over previous
//
#include <hip/hip_runtime.h>
#include <math.h>

#define BB 2
#define SEQ 2048
#define DMODEL 1024
#define NHH 16
#define DHH 64

typedef __bf16 bf16;
typedef __attribute__((ext_vector_type(8))) __bf16 bf16x8;
typedef __attribute__((ext_vector_type(4))) float f32x4;

// p = exp2(s*C1 + C2) = exp(0.125*s - 4)   [static-max softmax, 0.125*|s| <~ 2.5]
#define C1f 0.18033688011112042f
#define C2f -5.770780163555854f

// async global -> LDS, 16B per lane. LDS dest: wave-uniform base + lane*16.
__device__ __forceinline__ void gl_lds16(const bf16* g, bf16* l) {
  __builtin_amdgcn_global_load_lds(
      (const __attribute__((address_space(1))) void*)g,
      (__attribute__((address_space(3))) void*)l, 16, 0, 0);
}

// ---------------------------------------------------------------------------
// fp32 -> bf16 convert for both activations in one launch (blockIdx.y picks)
// ---------------------------------------------------------------------------
__global__ __launch_bounds__(256) void cvt2_bf16(const float* __restrict__ in0,
                                                 bf16* __restrict__ out0,
                                                 const float* __restrict__ in1,
                                                 bf16* __restrict__ out1, int n8) {
  int i = blockIdx.x * 256 + threadIdx.x;
  if (i >= n8) return;
  const float* in = blockIdx.y ? in1 : in0;
  bf16* out = blockIdx.y ? out1 : out0;
  const float4* p = (const float4*)in + 2 * (size_t)i;
  float4 a = p[0], b = p[1];
  bf16x8 v;
  v[0] = (bf16)a.x; v[1] = (bf16)a.y; v[2] = (bf16)a.z; v[3] = (bf16)a.w;
  v[4] = (bf16)b.x; v[5] = (bf16)b.y; v[6] = (bf16)b.z; v[7] = (bf16)b.w;
  *((bf16x8*)out + i) = v;
}

// ---------------------------------------------------------------------------
// Weight transpose+convert via LDS tile: Wt[n][k] = (bf16) W[k][n].
// ---------------------------------------------------------------------------
__global__ __launch_bounds__(256) void wt_cvt(const float* __restrict__ W0, const float* __restrict__ W1,
                                              const float* __restrict__ W2, const float* __restrict__ W3,
                                              bf16* __restrict__ O0, bf16* __restrict__ O1,
                                              bf16* __restrict__ O2, bf16* __restrict__ O3) {
  __shared__ bf16 T[64][72];
  const float* W; bf16* O;
  switch (blockIdx.z) {
    case 0: W = W0; O = O0; break;
    case 1: W = W1; O = O1; break;
    case 2: W = W2; O = O2; break;
    default: W = W3; O = O3; break;
  }
  const int n0 = blockIdx.x * 64, k0 = blockIdx.y * 64;
  const int t = threadIdx.x;
  {
    int k = t >> 2, ns = (t & 3) * 16;
    const float* g = W + (size_t)(k0 + k) * DMODEL + n0 + ns;
#pragma unroll
    for (int q = 0; q < 4; ++q) {
      float4 f = *(const float4*)(g + 4 * q);
      T[ns + 4 * q + 0][k] = (bf16)f.x;
      T[ns + 4 * q + 1][k] = (bf16)f.y;
      T[ns + 4 * q + 2][k] = (bf16)f.z;
      T[ns + 4 * q + 3][k] = (bf16)f.w;
    }
  }
  __syncthreads();
  {
    int n = t >> 2, ks = (t & 3) * 16;
    bf16x8 a = *(const bf16x8*)&T[n][ks];
    bf16x8 b = *(const bf16x8*)&T[n][ks + 8];
    bf16* o = O + (size_t)(n0 + n) * DMODEL + k0 + ks;
    *(bf16x8*)o = a;
    *(bf16x8*)(o + 8) = b;
  }
}

// ---------------------------------------------------------------------------
// bf16 MFMA GEMM, m97 structure: 128x128 tile, BK=64, global_load_lds
// width-16 staging (linear LDS dest, inverse-XOR-swizzled per-lane GLOBAL
// source, XOR-swizzled ds_read -> conflict-free), 2 barriers per K-step.
// 4 waves in 2x2, wave = 64x64 output (4x4 16x16 frags), 32 MFMA/K-step.
// LDS 32 KB -> ~3 blocks/CU (VGPR-bound), per m97 ~874-912 TF at this shape.
// ---------------------------------------------------------------------------
template <bool F32OUT>
__device__ __forceinline__ void gemm128_body(const bf16* __restrict__ A,
                                             const bf16* __restrict__ Bt,
                                             float* __restrict__ Cf,
                                             bf16* __restrict__ Cb,
                                             bf16* As, bf16* Bs) {
  const int t = threadIdx.x;
  const int lane = t & 63, wave = t >> 6;
  const int l15 = lane & 15, quad = lane >> 4;
  const int bm = blockIdx.y * 128, bn = blockIdx.x * 128;
  const int wr = wave >> 1, wc = wave & 1;

  // staging map: wave covers 32 rows (4 issues x 8 rows); lane -> (row, chunk)
  const int srow = wave * 32 + (lane >> 3);  // + j*8
  const int sc = lane & 7;
  const int ca = sc ^ ((lane >> 3) & 7);  // pre-swizzled global chunk (j*8 keeps row&7)
  const bf16* gA = A + (size_t)(bm + srow) * DMODEL + ca * 8;
  const bf16* gB = Bt + (size_t)(bn + srow) * DMODEL + ca * 8;
  bf16* lA = &As[wave * 32 * 64];
  bf16* lB = &Bs[wave * 32 * 64];

  f32x4 acc[4][4] = {};

  for (int kt = 0; kt < DMODEL / 64; ++kt) {
    const int kk = kt * 64;
#pragma unroll
    for (int j = 0; j < 4; ++j) {
      gl_lds16(gA + (size_t)(j * 8) * DMODEL + kk, lA + j * 8 * 64);
      gl_lds16(gB + (size_t)(j * 8) * DMODEL + kk, lB + j * 8 * 64);
    }
    __syncthreads();  // drains vmcnt: both LDS tiles ready
#pragma unroll
    for (int ks = 0; ks < 2; ++ks) {
      bf16x8 af[4], bfr[4];
#pragma unroll
      for (int mt = 0; mt < 4; ++mt) {
        int row = wr * 64 + mt * 16 + l15;
        int s = (ks * 4 + quad) ^ (row & 7);
        af[mt] = *(const bf16x8*)&As[row * 64 + s * 8];
      }
#pragma unroll
      for (int nt = 0; nt < 4; ++nt) {
        int row = wc * 64 + nt * 16 + l15;
        int s = (ks * 4 + quad) ^ (row & 7);
        bfr[nt] = *(const bf16x8*)&Bs[row * 64 + s * 8];
      }
#pragma unroll
      for (int mt = 0; mt < 4; ++mt)
#pragma unroll
        for (int nt = 0; nt < 4; ++nt)
          acc[mt][nt] = __builtin_amdgcn_mfma_f32_16x16x32_bf16(af[mt], bfr[nt], acc[mt][nt], 0, 0, 0);
    }
    __syncthreads();  // frag reads done before next stage overwrites
  }

#pragma unroll
  for (int mt = 0; mt < 4; ++mt)
#pragma unroll
    for (int nt = 0; nt < 4; ++nt)
#pragma unroll
      for (int r = 0; r < 4; ++r) {
        int row = bm + wr * 64 + mt * 16 + quad * 4 + r;
        int col = bn + wc * 64 + nt * 16 + l15;
        if (F32OUT) Cf[(size_t)row * DMODEL + col] = acc[mt][nt][r];
        else Cb[(size_t)row * DMODEL + col] = (bf16)acc[mt][nt][r];
      }
}

__global__ __launch_bounds__(256) void gemm_qkv(const bf16* __restrict__ qbf,
                                                const bf16* __restrict__ kvbf,
                                                const bf16* __restrict__ WtQ,
                                                const bf16* __restrict__ WtK,
                                                const bf16* __restrict__ WtV,
                                                bf16* __restrict__ Qb,
                                                bf16* __restrict__ Kb,
                                                bf16* __restrict__ Vb) {
  __shared__ bf16 As[128 * 64];
  __shared__ bf16 Bs[128 * 64];
  const bf16 *A, *Bt; bf16* C;
  switch (blockIdx.z) {
    case 0: A = qbf; Bt = WtQ; C = Qb; break;
    case 1: A = kvbf; Bt = WtK; C = Kb; break;
    default: A = kvbf; Bt = WtV; C = Vb; break;
  }
  gemm128_body<false>(A, Bt, nullptr, C, As, Bs);
}

__global__ __launch_bounds__(256) void gemm_out(const bf16* __restrict__ A,
                                                const bf16* __restrict__ Wt,
                                                float* __restrict__ C) {
  __shared__ bf16 As[128 * 64];
  __shared__ bf16 Bs[128 * 64];
  gemm128_body<true>(A, Wt, C, nullptr, As, Bs);
}

// ---------------------------------------------------------------------------
// MFMA flash attention (r0 best-measured version, 93.3 us): static-max
// softmax (hardware v_exp_f32), mask-free exp path, DOUBLE-BUFFERED K/V/mask
// LDS (one barrier per chunk, staging overlapped with compute). Block =
// (b,h,128 Q rows), 4 waves x 32 rows, BN=64 chunks. LDS 43.3 KB, grid 512
// (2/CU). h is the fast grid index so blocks sharing one (b,h) K/V slice
// (stride 32) land on one XCD.
// ---------------------------------------------------------------------------
__global__ __launch_bounds__(256) void attn_mfma(const bf16* __restrict__ Qb,
                                                 const bf16* __restrict__ Kb,
                                                 const bf16* __restrict__ Vb,
                                                 const int* __restrict__ maskp,
                                                 bf16* __restrict__ Ob) {
  __shared__ bf16 Ks[2][64 * 64];   // XOR-swizzled, unpadded (16 KB)
  __shared__ bf16 Vt[2][64][68];    // [d][n] (17 KB)
  __shared__ bf16 Ps[4][32][36];    // per-wave P round-trip (9.2 KB)
  __shared__ bf16 msk01[2][64];     // 1 = keep, 0 = masked

  const int blk = blockIdx.x;
  const int h = blk & 15;
  const int b = (blk >> 4) & 1;
  const int qb = blk >> 5;  // 0..15, 128-row tile
  const int t = threadIdx.x;
  const int wave = t >> 6, lane = t & 63;
  const int l15 = lane & 15, quad = lane >> 4;
  bf16(*PsW)[36] = Ps[wave];

  // staging maps
  const int kr = t >> 2, kq = t & 3;  // K: row kr (0..63), 16-elem quarter kq
  const bf16* gK = Kb + (size_t)(b * SEQ + kr) * DMODEL + h * 64 + kq * 16;
  const int s0 = (kq * 2) ^ (kr & 7), s1 = (kq * 2 + 1) ^ (kr & 7);
  const int nv = (t & 31) * 2, dc = (t >> 5) * 8;  // V: tokens nv,nv+1 x 8 d
  const bf16* gV = Vb + (size_t)(b * SEQ + nv) * DMODEL + h * 64 + dc;
  const int* gM = maskp + b * SEQ;

  // ---- stage chunk 0 into buffer 0 ----
  {
    bf16x8 k0 = *(const bf16x8*)(gK);
    bf16x8 k1 = *(const bf16x8*)(gK + 8);
    bf16x8 v0 = *(const bf16x8*)(gV);
    bf16x8 v1 = *(const bf16x8*)(gV + DMODEL);
    int2 m2 = *(const int2*)(gM + nv);
    *(bf16x8*)&Ks[0][kr * 64 + s0 * 8] = k0;
    *(bf16x8*)&Ks[0][kr * 64 + s1 * 8] = k1;
    union U { bf16x8 v; uint32_t dw[4]; } a, c;
    a.v = v0; c.v = v1;
    const uint32_t zA = m2.x ? 0u : 0xFFFFFFFFu;
    const uint32_t zB = m2.y ? 0u : 0xFFFFFFFFu;
#pragma unroll
    for (int d2 = 0; d2 < 4; ++d2) {
      uint32_t A0 = a.dw[d2] & zA, B0 = c.dw[d2] & zB;
      *(uint32_t*)&Vt[0][dc + 2 * d2 + 0][nv] = __builtin_amdgcn_perm(B0, A0, 0x05040100u);
      *(uint32_t*)&Vt[0][dc + 2 * d2 + 1][nv] = __builtin_amdgcn_perm(B0, A0, 0x07060302u);
    }
    if (t < 64) msk01[0][t] = gM[t] ? (bf16)0.f : (bf16)1.f;
  }

  // Q fragments (A-layout), loaded once
  bf16x8 qf[2][2];
#pragma unroll
  for (int mt = 0; mt < 2; ++mt)
#pragma unroll
    for (int ks = 0; ks < 2; ++ks) {
      const bf16* g = Qb + (size_t)(b * SEQ + qb * 128 + wave * 32 + mt * 16 + l15) * DMODEL +
                      h * 64 + ks * 32 + quad * 8;
      qf[mt][ks] = *(const bf16x8*)g;
    }

  f32x4 o[2][4] = {};
  f32x4 acc_l[2] = {};

  __syncthreads();  // buffer 0 ready

  for (int it = 0; it < SEQ / 64; ++it) {
    const int p = it & 1;
    const bool more = (it + 1) < SEQ / 64;
    // ---- issue next-chunk global loads (consumed at the bottom) ----
    bf16x8 kreg0, kreg1, vreg0, vreg1;
    int2 vm;
    int mreg = 0;
    if (more) {
      const int nn = (it + 1) * 64;
      const bf16* gK2 = gK + (size_t)nn * DMODEL;
      const bf16* gV2 = gV + (size_t)nn * DMODEL;
      kreg0 = *(const bf16x8*)(gK2);
      kreg1 = *(const bf16x8*)(gK2 + 8);
      vreg0 = *(const bf16x8*)(gV2);
      vreg1 = *(const bf16x8*)(gV2 + DMODEL);
      vm = *(const int2*)(gM + nn + nv);
      if (t < 64) mreg = gM[nn + t];
    }

    // ---- S = Q K^T : 2 mt x 4 nt C-frags (reads buffer p) ----
    f32x4 s[2][4] = {};
#pragma unroll
    for (int ks = 0; ks < 2; ++ks) {
      bf16x8 kf[4];
#pragma unroll
      for (int nt = 0; nt < 4; ++nt) {
        int row = nt * 16 + l15;
        int sl = (ks * 4 + quad) ^ (row & 7);
        kf[nt] = *(const bf16x8*)&Ks[p][row * 64 + sl * 8];
      }
#pragma unroll
      for (int mt = 0; mt < 2; ++mt)
#pragma unroll
        for (int nt = 0; nt < 4; ++nt)
          s[mt][nt] = __builtin_amdgcn_mfma_f32_16x16x32_bf16(qf[mt][ks], kf[nt], s[mt][nt], 0, 0, 0);
    }

    // ---- exp (v_exp_f32) + P round-trip + PV + l-accum, two 32-col ksteps ----
#pragma unroll
    for (int ks2 = 0; ks2 < 2; ++ks2) {
#pragma unroll
      for (int mt = 0; mt < 2; ++mt)
#pragma unroll
        for (int nt2 = 0; nt2 < 2; ++nt2)
#pragma unroll
          for (int r = 0; r < 4; ++r) {
            float pex = __builtin_amdgcn_exp2f(s[mt][ks2 * 2 + nt2][r] * C1f + C2f);
            PsW[mt * 16 + quad * 4 + r][nt2 * 16 + l15] = (bf16)pex;
          }
      bf16x8 pa[2], vb[4];
#pragma unroll
      for (int mt = 0; mt < 2; ++mt)
        pa[mt] = *(const bf16x8*)&PsW[mt * 16 + l15][quad * 8];
#pragma unroll
      for (int dt = 0; dt < 4; ++dt)
        vb[dt] = *(const bf16x8*)&Vt[p][dt * 16 + l15][ks2 * 32 + quad * 8];
      union OU { bf16x8 v; uint32_t dw[4]; } of;
      of.v = *(const bf16x8*)&msk01[p][ks2 * 32 + quad * 8];  // broadcast read
      const uint32_t zc = (l15 == 0) ? 0xFFFFFFFFu : 0u;
#pragma unroll
      for (int d = 0; d < 4; ++d) of.dw[d] &= zc;
#pragma unroll
      for (int mt = 0; mt < 2; ++mt) {
#pragma unroll
        for (int dt = 0; dt < 4; ++dt)
          o[mt][dt] = __builtin_amdgcn_mfma_f32_16x16x32_bf16(pa[mt], vb[dt], o[mt][dt], 0, 0, 0);
        acc_l[mt] = __builtin_amdgcn_mfma_f32_16x16x32_bf16(pa[mt], of.v, acc_l[mt], 0, 0, 0);
      }
    }

    // ---- write staged chunk into buffer 1-p ----
    if (more) {
      const int q = 1 - p;
      *(bf16x8*)&Ks[q][kr * 64 + s0 * 8] = kreg0;
      *(bf16x8*)&Ks[q][kr * 64 + s1 * 8] = kreg1;
      union U { bf16x8 v; uint32_t dw[4]; } a, c;
      a.v = vreg0; c.v = vreg1;
      const uint32_t zA = vm.x ? 0u : 0xFFFFFFFFu;
      const uint32_t zB = vm.y ? 0u : 0xFFFFFFFFu;
#pragma unroll
      for (int d2 = 0; d2 < 4; ++d2) {
        uint32_t A0 = a.dw[d2] & zA, B0 = c.dw[d2] & zB;
        *(uint32_t*)&Vt[q][dc + 2 * d2 + 0][nv] = __builtin_amdgcn_perm(B0, A0, 0x05040100u);
        *(uint32_t*)&Vt[q][dc + 2 * d2 + 1][nv] = __builtin_amdgcn_perm(B0, A0, 0x07060302u);
      }
      if (t < 64) msk01[q][t] = mreg ? (bf16)0.f : (bf16)1.f;
    }
    __syncthreads();  // buffer 1-p written, buffer p reads complete
  }

  // epilogue: l lives in col 0 (lanes quad*16); broadcast, normalize, store
#pragma unroll
  for (int mt = 0; mt < 2; ++mt)
#pragma unroll
    for (int r = 0; r < 4; ++r) {
      float lv = __shfl(acc_l[mt][r], lane & 48);
      float inv = 1.f / lv;
      int row = b * SEQ + qb * 128 + wave * 32 + mt * 16 + quad * 4 + r;
#pragma unroll
      for (int dt = 0; dt < 4; ++dt) {
        int col = h * 64 + dt * 16 + l15;
        Ob[(size_t)row * DMODEL + col] = (bf16)(o[mt][dt][r] * inv);
      }
    }
}

// ---------------------------------------------------------------------------
extern "C" void kernel_launch(void* const* d_in, const int* in_sizes, int n_in,
                              void* d_out, int out_size, void* d_ws, size_t ws_size,
                              hipStream_t stream) {
  (void)in_sizes; (void)n_in; (void)out_size; (void)ws_size;
  const float* query = (const float*)d_in[0];
  const float* key_value = (const float*)d_in[1];
  const int* mask = (const int*)d_in[2];
  const float* W_Q = (const float*)d_in[3];
  const float* W_K = (const float*)d_in[4];
  const float* W_V = (const float*)d_in[5];
  const float* W_O = (const float*)d_in[6];
  float* out = (float*)d_out;

  const size_t TOK = (size_t)BB * SEQ;  // 4096
  const size_t TE = TOK * DMODEL;       // 4,194,304 elems
  char* w = (char*)d_ws;
  bf16* qbf = (bf16*)w;   w += TE * 2;
  bf16* kvbf = (bf16*)w;  w += TE * 2;
  bf16* WtQ = (bf16*)w;   w += (size_t)DMODEL * DMODEL * 2;
  bf16* WtK = (bf16*)w;   w += (size_t)DMODEL * DMODEL * 2;
  bf16* WtV = (bf16*)w;   w += (size_t)DMODEL * DMODEL * 2;
  bf16* WtO = (bf16*)w;   w += (size_t)DMODEL * DMODEL * 2;
  bf16* Qbuf = (bf16*)w;  w += TE * 2;
  bf16* Kbuf = (bf16*)w;  w += TE * 2;
  bf16* Vbuf = (bf16*)w;  w += TE * 2;
  bf16* Obuf = (bf16*)w;  w += TE * 2;

  cvt2_bf16<<<dim3(TE / 8 / 256, 2), 256, 0, stream>>>(query, qbf, key_value, kvbf, TE / 8);
  wt_cvt<<<dim3(16, 16, 4), 256, 0, stream>>>(W_Q, W_K, W_V, W_O, WtQ, WtK, WtV, WtO);

  gemm_qkv<<<dim3(DMODEL / 128, TOK / 128, 3), 256, 0, stream>>>(qbf, kvbf, WtQ, WtK, WtV,
                                                                 Qbuf, Kbuf, Vbuf);

  attn_mfma<<<BB * NHH * (SEQ / 128), 256, 0, stream>>>(Qbuf, Kbuf, Vbuf, mask, Obuf);

  gemm_out<<<dim3(DMODEL / 128, TOK / 128), 256, 0, stream>>>(Obuf, WtO, out);
}

// Round 4
// 238.667 us; speedup vs baseline: 1.0347x; 1.0079x over previous
//
#include <hip/hip_runtime.h>
#include <math.h>

#define BB 2
#define SEQ 2048
#define DMODEL 1024
#define NHH 16
#define DHH 64

typedef __bf16 bf16;
typedef __attribute__((ext_vector_type(8))) __bf16 bf16x8;
typedef __attribute__((ext_vector_type(4))) float f32x4;

// p = exp2(s*C1 + C2) = exp(0.125*s - 4)   [static-max softmax, 0.125*|s| <~ 2.5]
#define C1f 0.18033688011112042f
#define C2f -5.770780163555854f

// async global -> LDS, 16B per lane. LDS dest: wave-uniform base + lane*16.
__device__ __forceinline__ void gl_lds16(const bf16* g, bf16* l) {
  __builtin_amdgcn_global_load_lds(
      (const __attribute__((address_space(1))) void*)g,
      (__attribute__((address_space(3))) void*)l, 16, 0, 0);
}

// ---------------------------------------------------------------------------
// fp32 -> bf16 convert for both activations in one launch (blockIdx.y picks)
// ---------------------------------------------------------------------------
__global__ __launch_bounds__(256) void cvt2_bf16(const float* __restrict__ in0,
                                                 bf16* __restrict__ out0,
                                                 const float* __restrict__ in1,
                                                 bf16* __restrict__ out1, int n8) {
  int i = blockIdx.x * 256 + threadIdx.x;
  if (i >= n8) return;
  const float* in = blockIdx.y ? in1 : in0;
  bf16* out = blockIdx.y ? out1 : out0;
  const float4* p = (const float4*)in + 2 * (size_t)i;
  float4 a = p[0], b = p[1];
  bf16x8 v;
  v[0] = (bf16)a.x; v[1] = (bf16)a.y; v[2] = (bf16)a.z; v[3] = (bf16)a.w;
  v[4] = (bf16)b.x; v[5] = (bf16)b.y; v[6] = (bf16)b.z; v[7] = (bf16)b.w;
  *((bf16x8*)out + i) = v;
}

// ---------------------------------------------------------------------------
// Weight transpose+convert via LDS tile: Wt[n][k] = (bf16) W[k][n].
// ---------------------------------------------------------------------------
__global__ __launch_bounds__(256) void wt_cvt(const float* __restrict__ W0, const float* __restrict__ W1,
                                              const float* __restrict__ W2, const float* __restrict__ W3,
                                              bf16* __restrict__ O0, bf16* __restrict__ O1,
                                              bf16* __restrict__ O2, bf16* __restrict__ O3) {
  __shared__ bf16 T[64][72];
  const float* W; bf16* O;
  switch (blockIdx.z) {
    case 0: W = W0; O = O0; break;
    case 1: W = W1; O = O1; break;
    case 2: W = W2; O = O2; break;
    default: W = W3; O = O3; break;
  }
  const int n0 = blockIdx.x * 64, k0 = blockIdx.y * 64;
  const int t = threadIdx.x;
  {
    int k = t >> 2, ns = (t & 3) * 16;
    const float* g = W + (size_t)(k0 + k) * DMODEL + n0 + ns;
#pragma unroll
    for (int q = 0; q < 4; ++q) {
      float4 f = *(const float4*)(g + 4 * q);
      T[ns + 4 * q + 0][k] = (bf16)f.x;
      T[ns + 4 * q + 1][k] = (bf16)f.y;
      T[ns + 4 * q + 2][k] = (bf16)f.z;
      T[ns + 4 * q + 3][k] = (bf16)f.w;
    }
  }
  __syncthreads();
  {
    int n = t >> 2, ks = (t & 3) * 16;
    bf16x8 a = *(const bf16x8*)&T[n][ks];
    bf16x8 b = *(const bf16x8*)&T[n][ks + 8];
    bf16* o = O + (size_t)(n0 + n) * DMODEL + k0 + ks;
    *(bf16x8*)o = a;
    *(bf16x8*)(o + 8) = b;
  }
}

// ---------------------------------------------------------------------------
// bf16 MFMA GEMM, 128x128 tile, BK=64, TRUE DOUBLE-BUFFERED LDS (T3 minimum
// 2-phase): stage NEXT K-tile via global_load_lds width-16 BEFORE computing
// the current one; ONE barrier per K-step (its vmcnt(0)+lgkmcnt(0) drain
// both completes the prefetch and protects the buffer swap). Buffers are
// statically distinct arrays (compile-time alternation, no runtime-indexed
// LDS pointers) so no conservative waitcnt lands before the ds_reads.
// Linear LDS dest + inverse-XOR-swizzled per-lane GLOBAL source + swizzled
// ds_read -> conflict-free. 4 waves 2x2, wave = 64x64 (4x4 frags).
// LDS 64 KB -> 2 blocks/CU.
// ---------------------------------------------------------------------------
template <bool F32OUT>
__device__ __forceinline__ void gemm128_body(const bf16* __restrict__ A,
                                             const bf16* __restrict__ Bt,
                                             float* __restrict__ Cf,
                                             bf16* __restrict__ Cb,
                                             bf16* As0, bf16* Bs0,
                                             bf16* As1, bf16* Bs1) {
  const int t = threadIdx.x;
  const int lane = t & 63, wave = t >> 6;
  const int l15 = lane & 15, quad = lane >> 4;
  const int bm = blockIdx.y * 128, bn = blockIdx.x * 128;
  const int wr = wave >> 1, wc = wave & 1;

  // staging map: wave covers 32 rows (4 issues x 8 rows); lane -> (row, chunk)
  const int srow = wave * 32 + (lane >> 3);  // + j*8
  const int sc = lane & 7;
  const int ca = sc ^ ((lane >> 3) & 7);  // pre-swizzled global chunk (j*8 keeps row&7)
  const bf16* gA = A + (size_t)(bm + srow) * DMODEL + ca * 8;
  const bf16* gB = Bt + (size_t)(bn + srow) * DMODEL + ca * 8;
  const int lo = wave * 32 * 64;  // wave's linear LDS base (elements)

  f32x4 acc[4][4] = {};

  // ---- stage(kt, As, Bs): issue 8 async 16B/lane loads ----
#define STAGE(KT, AS, BS)                                              \
  {                                                                    \
    const int kk = (KT) * 64;                                          \
    _Pragma("unroll") for (int j = 0; j < 4; ++j) {                    \
      gl_lds16(gA + (size_t)(j * 8) * DMODEL + kk, (AS) + lo + j * 512); \
      gl_lds16(gB + (size_t)(j * 8) * DMODEL + kk, (BS) + lo + j * 512); \
    }                                                                  \
  }

  // ---- compute(As, Bs): 2 ks halves x 16 MFMA ----
#define COMPUTE(AS, BS)                                                \
  {                                                                    \
    _Pragma("unroll") for (int ks = 0; ks < 2; ++ks) {                 \
      bf16x8 af[4], bfr[4];                                            \
      _Pragma("unroll") for (int mt = 0; mt < 4; ++mt) {               \
        int row = wr * 64 + mt * 16 + l15;                             \
        int s = (ks * 4 + quad) ^ (row & 7);                           \
        af[mt] = *(const bf16x8*)&(AS)[row * 64 + s * 8];              \
      }                                                                \
      _Pragma("unroll") for (int nt = 0; nt < 4; ++nt) {               \
        int row = wc * 64 + nt * 16 + l15;                             \
        int s = (ks * 4 + quad) ^ (row & 7);                           \
        bfr[nt] = *(const bf16x8*)&(BS)[row * 64 + s * 8];             \
      }                                                                \
      _Pragma("unroll") for (int mt = 0; mt < 4; ++mt)                 \
          _Pragma("unroll") for (int nt = 0; nt < 4; ++nt)             \
              acc[mt][nt] = __builtin_amdgcn_mfma_f32_16x16x32_bf16(   \
                  af[mt], bfr[nt], acc[mt][nt], 0, 0, 0);              \
    }                                                                  \
  }

  STAGE(0, As0, Bs0);
  __syncthreads();  // prefetch 0 landed

  for (int kt = 0; kt < DMODEL / 64; kt += 2) {
    if (kt + 1 < DMODEL / 64) STAGE(kt + 1, As1, Bs1);
    COMPUTE(As0, Bs0);
    __syncthreads();  // buf1 landed; buf0 reads done
    if (kt + 2 < DMODEL / 64) STAGE(kt + 2, As0, Bs0);
    COMPUTE(As1, Bs1);
    __syncthreads();  // buf0 landed; buf1 reads done
  }
#undef STAGE
#undef COMPUTE

#pragma unroll
  for (int mt = 0; mt < 4; ++mt)
#pragma unroll
    for (int nt = 0; nt < 4; ++nt)
#pragma unroll
      for (int r = 0; r < 4; ++r) {
        int row = bm + wr * 64 + mt * 16 + quad * 4 + r;
        int col = bn + wc * 64 + nt * 16 + l15;
        if (F32OUT) Cf[(size_t)row * DMODEL + col] = acc[mt][nt][r];
        else Cb[(size_t)row * DMODEL + col] = (bf16)acc[mt][nt][r];
      }
}

__global__ __launch_bounds__(256, 2) void gemm_qkv(const bf16* __restrict__ qbf,
                                                   const bf16* __restrict__ kvbf,
                                                   const bf16* __restrict__ WtQ,
                                                   const bf16* __restrict__ WtK,
                                                   const bf16* __restrict__ WtV,
                                                   bf16* __restrict__ Qb,
                                                   bf16* __restrict__ Kb,
                                                   bf16* __restrict__ Vb) {
  __shared__ bf16 As0[128 * 64], Bs0[128 * 64];
  __shared__ bf16 As1[128 * 64], Bs1[128 * 64];
  const bf16 *A, *Bt; bf16* C;
  switch (blockIdx.z) {
    case 0: A = qbf; Bt = WtQ; C = Qb; break;
    case 1: A = kvbf; Bt = WtK; C = Kb; break;
    default: A = kvbf; Bt = WtV; C = Vb; break;
  }
  gemm128_body<false>(A, Bt, nullptr, C, As0, Bs0, As1, Bs1);
}

__global__ __launch_bounds__(256, 2) void gemm_out(const bf16* __restrict__ A,
                                                   const bf16* __restrict__ Wt,
                                                   float* __restrict__ C) {
  __shared__ bf16 As0[128 * 64], Bs0[128 * 64];
  __shared__ bf16 As1[128 * 64], Bs1[128 * 64];
  gemm128_body<true>(A, Wt, C, nullptr, As0, Bs0, As1, Bs1);
}

// ---------------------------------------------------------------------------
// MFMA flash attention (r0 best-measured version, 93.3 us): static-max
// softmax (hardware v_exp_f32), mask-free exp path, DOUBLE-BUFFERED K/V/mask
// LDS (one barrier per chunk, staging overlapped with compute). Block =
// (b,h,128 Q rows), 4 waves x 32 rows, BN=64 chunks. LDS 43.3 KB, grid 512
// (2/CU). h is the fast grid index so blocks sharing one (b,h) K/V slice
// (stride 32) land on one XCD.
// ---------------------------------------------------------------------------
__global__ __launch_bounds__(256) void attn_mfma(const bf16* __restrict__ Qb,
                                                 const bf16* __restrict__ Kb,
                                                 const bf16* __restrict__ Vb,
                                                 const int* __restrict__ maskp,
                                                 bf16* __restrict__ Ob) {
  __shared__ bf16 Ks[2][64 * 64];   // XOR-swizzled, unpadded (16 KB)
  __shared__ bf16 Vt[2][64][68];    // [d][n] (17 KB)
  __shared__ bf16 Ps[4][32][36];    // per-wave P round-trip (9.2 KB)
  __shared__ bf16 msk01[2][64];     // 1 = keep, 0 = masked

  const int blk = blockIdx.x;
  const int h = blk & 15;
  const int b = (blk >> 4) & 1;
  const int qb = blk >> 5;  // 0..15, 128-row tile
  const int t = threadIdx.x;
  const int wave = t >> 6, lane = t & 63;
  const int l15 = lane & 15, quad = lane >> 4;
  bf16(*PsW)[36] = Ps[wave];

  // staging maps
  const int kr = t >> 2, kq = t & 3;  // K: row kr (0..63), 16-elem quarter kq
  const bf16* gK = Kb + (size_t)(b * SEQ + kr) * DMODEL + h * 64 + kq * 16;
  const int s0 = (kq * 2) ^ (kr & 7), s1 = (kq * 2 + 1) ^ (kr & 7);
  const int nv = (t & 31) * 2, dc = (t >> 5) * 8;  // V: tokens nv,nv+1 x 8 d
  const bf16* gV = Vb + (size_t)(b * SEQ + nv) * DMODEL + h * 64 + dc;
  const int* gM = maskp + b * SEQ;

  // ---- stage chunk 0 into buffer 0 ----
  {
    bf16x8 k0 = *(const bf16x8*)(gK);
    bf16x8 k1 = *(const bf16x8*)(gK + 8);
    bf16x8 v0 = *(const bf16x8*)(gV);
    bf16x8 v1 = *(const bf16x8*)(gV + DMODEL);
    int2 m2 = *(const int2*)(gM + nv);
    *(bf16x8*)&Ks[0][kr * 64 + s0 * 8] = k0;
    *(bf16x8*)&Ks[0][kr * 64 + s1 * 8] = k1;
    union U { bf16x8 v; uint32_t dw[4]; } a, c;
    a.v = v0; c.v = v1;
    const uint32_t zA = m2.x ? 0u : 0xFFFFFFFFu;
    const uint32_t zB = m2.y ? 0u : 0xFFFFFFFFu;
#pragma unroll
    for (int d2 = 0; d2 < 4; ++d2) {
      uint32_t A0 = a.dw[d2] & zA, B0 = c.dw[d2] & zB;
      *(uint32_t*)&Vt[0][dc + 2 * d2 + 0][nv] = __builtin_amdgcn_perm(B0, A0, 0x05040100u);
      *(uint32_t*)&Vt[0][dc + 2 * d2 + 1][nv] = __builtin_amdgcn_perm(B0, A0, 0x07060302u);
    }
    if (t < 64) msk01[0][t] = gM[t] ? (bf16)0.f : (bf16)1.f;
  }

  // Q fragments (A-layout), loaded once
  bf16x8 qf[2][2];
#pragma unroll
  for (int mt = 0; mt < 2; ++mt)
#pragma unroll
    for (int ks = 0; ks < 2; ++ks) {
      const bf16* g = Qb + (size_t)(b * SEQ + qb * 128 + wave * 32 + mt * 16 + l15) * DMODEL +
                      h * 64 + ks * 32 + quad * 8;
      qf[mt][ks] = *(const bf16x8*)g;
    }

  f32x4 o[2][4] = {};
  f32x4 acc_l[2] = {};

  __syncthreads();  // buffer 0 ready

  for (int it = 0; it < SEQ / 64; ++it) {
    const int p = it & 1;
    const bool more = (it + 1) < SEQ / 64;
    // ---- issue next-chunk global loads (consumed at the bottom) ----
    bf16x8 kreg0, kreg1, vreg0, vreg1;
    int2 vm;
    int mreg = 0;
    if (more) {
      const int nn = (it + 1) * 64;
      const bf16* gK2 = gK + (size_t)nn * DMODEL;
      const bf16* gV2 = gV + (size_t)nn * DMODEL;
      kreg0 = *(const bf16x8*)(gK2);
      kreg1 = *(const bf16x8*)(gK2 + 8);
      vreg0 = *(const bf16x8*)(gV2);
      vreg1 = *(const bf16x8*)(gV2 + DMODEL);
      vm = *(const int2*)(gM + nn + nv);
      if (t < 64) mreg = gM[nn + t];
    }

    // ---- S = Q K^T : 2 mt x 4 nt C-frags (reads buffer p) ----
    f32x4 s[2][4] = {};
#pragma unroll
    for (int ks = 0; ks < 2; ++ks) {
      bf16x8 kf[4];
#pragma unroll
      for (int nt = 0; nt < 4; ++nt) {
        int row = nt * 16 + l15;
        int sl = (ks * 4 + quad) ^ (row & 7);
        kf[nt] = *(const bf16x8*)&Ks[p][row * 64 + sl * 8];
      }
#pragma unroll
      for (int mt = 0; mt < 2; ++mt)
#pragma unroll
        for (int nt = 0; nt < 4; ++nt)
          s[mt][nt] = __builtin_amdgcn_mfma_f32_16x16x32_bf16(qf[mt][ks], kf[nt], s[mt][nt], 0, 0, 0);
    }

    // ---- exp (v_exp_f32) + P round-trip + PV + l-accum, two 32-col ksteps ----
#pragma unroll
    for (int ks2 = 0; ks2 < 2; ++ks2) {
#pragma unroll
      for (int mt = 0; mt < 2; ++mt)
#pragma unroll
        for (int nt2 = 0; nt2 < 2; ++nt2)
#pragma unroll
          for (int r = 0; r < 4; ++r) {
            float pex = __builtin_amdgcn_exp2f(s[mt][ks2 * 2 + nt2][r] * C1f + C2f);
            PsW[mt * 16 + quad * 4 + r][nt2 * 16 + l15] = (bf16)pex;
          }
      bf16x8 pa[2], vb[4];
#pragma unroll
      for (int mt = 0; mt < 2; ++mt)
        pa[mt] = *(const bf16x8*)&PsW[mt * 16 + l15][quad * 8];
#pragma unroll
      for (int dt = 0; dt < 4; ++dt)
        vb[dt] = *(const bf16x8*)&Vt[p][dt * 16 + l15][ks2 * 32 + quad * 8];
      union OU { bf16x8 v; uint32_t dw[4]; } of;
      of.v = *(const bf16x8*)&msk01[p][ks2 * 32 + quad * 8];  // broadcast read
      const uint32_t zc = (l15 == 0) ? 0xFFFFFFFFu : 0u;
#pragma unroll
      for (int d = 0; d < 4; ++d) of.dw[d] &= zc;
#pragma unroll
      for (int mt = 0; mt < 2; ++mt) {
#pragma unroll
        for (int dt = 0; dt < 4; ++dt)
          o[mt][dt] = __builtin_amdgcn_mfma_f32_16x16x32_bf16(pa[mt], vb[dt], o[mt][dt], 0, 0, 0);
        acc_l[mt] = __builtin_amdgcn_mfma_f32_16x16x32_bf16(pa[mt], of.v, acc_l[mt], 0, 0, 0);
      }
    }

    // ---- write staged chunk into buffer 1-p ----
    if (more) {
      const int q = 1 - p;
      *(bf16x8*)&Ks[q][kr * 64 + s0 * 8] = kreg0;
      *(bf16x8*)&Ks[q][kr * 64 + s1 * 8] = kreg1;
      union U { bf16x8 v; uint32_t dw[4]; } a, c;
      a.v = vreg0; c.v = vreg1;
      const uint32_t zA = vm.x ? 0u : 0xFFFFFFFFu;
      const uint32_t zB = vm.y ? 0u : 0xFFFFFFFFu;
#pragma unroll
      for (int d2 = 0; d2 < 4; ++d2) {
        uint32_t A0 = a.dw[d2] & zA, B0 = c.dw[d2] & zB;
        *(uint32_t*)&Vt[q][dc + 2 * d2 + 0][nv] = __builtin_amdgcn_perm(B0, A0, 0x05040100u);
        *(uint32_t*)&Vt[q][dc + 2 * d2 + 1][nv] = __builtin_amdgcn_perm(B0, A0, 0x07060302u);
      }
      if (t < 64) msk01[q][t] = mreg ? (bf16)0.f : (bf16)1.f;
    }
    __syncthreads();  // buffer 1-p written, buffer p reads complete
  }

  // epilogue: l lives in col 0 (lanes quad*16); broadcast, normalize, store
#pragma unroll
  for (int mt = 0; mt < 2; ++mt)
#pragma unroll
    for (int r = 0; r < 4; ++r) {
      float lv = __shfl(acc_l[mt][r], lane & 48);
      float inv = 1.f / lv;
      int row = b * SEQ + qb * 128 + wave * 32 + mt * 16 + quad * 4 + r;
#pragma unroll
      for (int dt = 0; dt < 4; ++dt) {
        int col = h * 64 + dt * 16 + l15;
        Ob[(size_t)row * DMODEL + col] = (bf16)(o[mt][dt][r] * inv);
      }
    }
}

// ---------------------------------------------------------------------------
extern "C" void kernel_launch(void* const* d_in, const int* in_sizes, int n_in,
                              void* d_out, int out_size, void* d_ws, size_t ws_size,
                              hipStream_t stream) {
  (void)in_sizes; (void)n_in; (void)out_size; (void)ws_size;
  const float* query = (const float*)d_in[0];
  const float* key_value = (const float*)d_in[1];
  const int* mask = (const int*)d_in[2];
  const float* W_Q = (const float*)d_in[3];
  const float* W_K = (const float*)d_in[4];
  const float* W_V = (const float*)d_in[5];
  const float* W_O = (const float*)d_in[6];
  float* out = (float*)d_out;

  const size_t TOK = (size_t)BB * SEQ;  // 4096
  const size_t TE = TOK * DMODEL;       // 4,194,304 elems
  char* w = (char*)d_ws;
  bf16* qbf = (bf16*)w;   w += TE * 2;
  bf16* kvbf = (bf16*)w;  w += TE * 2;
  bf16* WtQ = (bf16*)w;   w += (size_t)DMODEL * DMODEL * 2;
  bf16* WtK = (bf16*)w;   w += (size_t)DMODEL * DMODEL * 2;
  bf16* WtV = (bf16*)w;   w += (size_t)DMODEL * DMODEL * 2;
  bf16* WtO = (bf16*)w;   w += (size_t)DMODEL * DMODEL * 2;
  bf16* Qbuf = (bf16*)w;  w += TE * 2;
  bf16* Kbuf = (bf16*)w;  w += TE * 2;
  bf16* Vbuf = (bf16*)w;  w += TE * 2;
  bf16* Obuf = (bf16*)w;  w += TE * 2;

  cvt2_bf16<<<dim3(TE / 8 / 256, 2), 256, 0, stream>>>(query, qbf, key_value, kvbf, TE / 8);
  wt_cvt<<<dim3(16, 16, 4), 256, 0, stream>>>(W_Q, W_K, W_V, W_O, WtQ, WtK, WtV, WtO);

  gemm_qkv<<<dim3(DMODEL / 128, TOK / 128, 3), 256, 0, stream>>>(qbf, kvbf, WtQ, WtK, WtV,
                                                                 Qbuf, Kbuf, Vbuf);

  attn_mfma<<<BB * NHH * (SEQ / 128), 256, 0, stream>>>(Qbuf, Kbuf, Vbuf, mask, Obuf);

  gemm_out<<<dim3(DMODEL / 128, TOK / 128), 256, 0, stream>>>(Obuf, WtO, out);
}

// Round 5
// 212.537 us; speedup vs baseline: 1.1619x; 1.1229x over previous
//
#include <hip/hip_runtime.h>
#include <math.h>

#define BB 2
#define SEQ 2048
#define DMODEL 1024
#define NHH 16
#define DHH 64

typedef __bf16 bf16;
typedef __attribute__((ext_vector_type(8))) __bf16 bf16x8;
typedef __attribute__((ext_vector_type(4))) float f32x4;
typedef __attribute__((ext_vector_type(16))) float f32x16;

// p = exp2(s*C1 + C2) = exp(0.125*s - 4)   [static-max softmax, 0.125*|s| <~ 2.5]
#define C1f 0.18033688011112042f
#define C2f -5.770780163555854f

__device__ __forceinline__ uint32_t cvtpk_bf16(float lo, float hi) {
  uint32_t r;
  asm("v_cvt_pk_bf16_f32 %0, %1, %2" : "=v"(r) : "v"(lo), "v"(hi));
  return r;
}
__device__ __forceinline__ void pl32swap(uint32_t& a, uint32_t& b) {
  asm("v_permlane32_swap_b32 %0, %1" : "+v"(a), "+v"(b));
}

// async global -> LDS, 16B per lane. LDS dest: wave-uniform base + lane*16.
__device__ __forceinline__ void gl_lds16(const bf16* g, bf16* l) {
  __builtin_amdgcn_global_load_lds(
      (const __attribute__((address_space(1))) void*)g,
      (__attribute__((address_space(3))) void*)l, 16, 0, 0);
}

// ---------------------------------------------------------------------------
// PREP (fused): blocks [0,1024) transpose+convert the 4 weight matrices
// (old wt_cvt); blocks [1024,5120) convert the two activations (old
// cvt2_bf16). One dispatch instead of two.
// ---------------------------------------------------------------------------
__global__ __launch_bounds__(256) void prep(const float* __restrict__ query,
                                            const float* __restrict__ key_value,
                                            bf16* __restrict__ qbf,
                                            bf16* __restrict__ kvbf,
                                            const float* __restrict__ W0, const float* __restrict__ W1,
                                            const float* __restrict__ W2, const float* __restrict__ W3,
                                            bf16* __restrict__ O0, bf16* __restrict__ O1,
                                            bf16* __restrict__ O2, bf16* __restrict__ O3) {
  __shared__ bf16 T[64][72];
  const int bid = blockIdx.x;
  const int t = threadIdx.x;
  if (bid >= 1024) {
    // activation convert: 2048 blocks per tensor
    const int bidc = bid - 1024;
    const float* in = (bidc >> 11) ? key_value : query;
    bf16* out = (bidc >> 11) ? kvbf : qbf;
    const int i = (bidc & 2047) * 256 + t;
    const float4* p = (const float4*)in + 2 * (size_t)i;
    float4 a = p[0], b = p[1];
    bf16x8 v;
    v[0] = (bf16)a.x; v[1] = (bf16)a.y; v[2] = (bf16)a.z; v[3] = (bf16)a.w;
    v[4] = (bf16)b.x; v[5] = (bf16)b.y; v[6] = (bf16)b.z; v[7] = (bf16)b.w;
    *((bf16x8*)out + i) = v;
    return;
  }
  // weight transpose+convert: Wt[n][k] = (bf16) W[k][n]
  const float* W; bf16* O;
  switch (bid >> 8) {
    case 0: W = W0; O = O0; break;
    case 1: W = W1; O = O1; break;
    case 2: W = W2; O = O2; break;
    default: W = W3; O = O3; break;
  }
  const int n0 = (bid & 15) * 64, k0 = ((bid >> 4) & 15) * 64;
  {
    int k = t >> 2, ns = (t & 3) * 16;
    const float* g = W + (size_t)(k0 + k) * DMODEL + n0 + ns;
#pragma unroll
    for (int q = 0; q < 4; ++q) {
      float4 f = *(const float4*)(g + 4 * q);
      T[ns + 4 * q + 0][k] = (bf16)f.x;
      T[ns + 4 * q + 1][k] = (bf16)f.y;
      T[ns + 4 * q + 2][k] = (bf16)f.z;
      T[ns + 4 * q + 3][k] = (bf16)f.w;
    }
  }
  __syncthreads();
  {
    int n = t >> 2, ks = (t & 3) * 16;
    bf16x8 a = *(const bf16x8*)&T[n][ks];
    bf16x8 b = *(const bf16x8*)&T[n][ks + 8];
    bf16* o = O + (size_t)(n0 + n) * DMODEL + k0 + ks;
    *(bf16x8*)o = a;
    *(bf16x8*)(o + 8) = b;
  }
}

// ---------------------------------------------------------------------------
// bf16 MFMA GEMM, 128x128 tile, BK=64, double-buffered global_load_lds
// staging (r4 structure, unchanged this round).
// ---------------------------------------------------------------------------
template <bool F32OUT>
__device__ __forceinline__ void gemm128_body(const bf16* __restrict__ A,
                                             const bf16* __restrict__ Bt,
                                             float* __restrict__ Cf,
                                             bf16* __restrict__ Cb,
                                             bf16* As0, bf16* Bs0,
                                             bf16* As1, bf16* Bs1) {
  const int t = threadIdx.x;
  const int lane = t & 63, wave = t >> 6;
  const int l15 = lane & 15, quad = lane >> 4;
  const int bm = blockIdx.y * 128, bn = blockIdx.x * 128;
  const int wr = wave >> 1, wc = wave & 1;

  const int srow = wave * 32 + (lane >> 3);  // + j*8
  const int sc = lane & 7;
  const int ca = sc ^ ((lane >> 3) & 7);  // pre-swizzled global chunk
  const bf16* gA = A + (size_t)(bm + srow) * DMODEL + ca * 8;
  const bf16* gB = Bt + (size_t)(bn + srow) * DMODEL + ca * 8;
  const int lo = wave * 32 * 64;

  f32x4 acc[4][4] = {};

#define STAGE(KT, AS, BS)                                                \
  {                                                                      \
    const int kk = (KT) * 64;                                            \
    _Pragma("unroll") for (int j = 0; j < 4; ++j) {                      \
      gl_lds16(gA + (size_t)(j * 8) * DMODEL + kk, (AS) + lo + j * 512); \
      gl_lds16(gB + (size_t)(j * 8) * DMODEL + kk, (BS) + lo + j * 512); \
    }                                                                    \
  }

#define COMPUTE(AS, BS)                                                \
  {                                                                    \
    _Pragma("unroll") for (int ks = 0; ks < 2; ++ks) {                 \
      bf16x8 af[4], bfr[4];                                            \
      _Pragma("unroll") for (int mt = 0; mt < 4; ++mt) {               \
        int row = wr * 64 + mt * 16 + l15;                             \
        int s = (ks * 4 + quad) ^ (row & 7);                           \
        af[mt] = *(const bf16x8*)&(AS)[row * 64 + s * 8];              \
      }                                                                \
      _Pragma("unroll") for (int nt = 0; nt < 4; ++nt) {               \
        int row = wc * 64 + nt * 16 + l15;                             \
        int s = (ks * 4 + quad) ^ (row & 7);                           \
        bfr[nt] = *(const bf16x8*)&(BS)[row * 64 + s * 8];             \
      }                                                                \
      _Pragma("unroll") for (int mt = 0; mt < 4; ++mt)                 \
          _Pragma("unroll") for (int nt = 0; nt < 4; ++nt)             \
              acc[mt][nt] = __builtin_amdgcn_mfma_f32_16x16x32_bf16(   \
                  af[mt], bfr[nt], acc[mt][nt], 0, 0, 0);              \
    }                                                                  \
  }

  STAGE(0, As0, Bs0);
  __syncthreads();

  for (int kt = 0; kt < DMODEL / 64; kt += 2) {
    if (kt + 1 < DMODEL / 64) STAGE(kt + 1, As1, Bs1);
    COMPUTE(As0, Bs0);
    __syncthreads();
    if (kt + 2 < DMODEL / 64) STAGE(kt + 2, As0, Bs0);
    COMPUTE(As1, Bs1);
    __syncthreads();
  }
#undef STAGE
#undef COMPUTE

#pragma unroll
  for (int mt = 0; mt < 4; ++mt)
#pragma unroll
    for (int nt = 0; nt < 4; ++nt)
#pragma unroll
      for (int r = 0; r < 4; ++r) {
        int row = bm + wr * 64 + mt * 16 + quad * 4 + r;
        int col = bn + wc * 64 + nt * 16 + l15;
        if (F32OUT) Cf[(size_t)row * DMODEL + col] = acc[mt][nt][r];
        else Cb[(size_t)row * DMODEL + col] = (bf16)acc[mt][nt][r];
      }
}

__global__ __launch_bounds__(256, 2) void gemm_qkv(const bf16* __restrict__ qbf,
                                                   const bf16* __restrict__ kvbf,
                                                   const bf16* __restrict__ WtQ,
                                                   const bf16* __restrict__ WtK,
                                                   const bf16* __restrict__ WtV,
                                                   bf16* __restrict__ Qb,
                                                   bf16* __restrict__ Kb,
                                                   bf16* __restrict__ Vb) {
  __shared__ bf16 As0[128 * 64], Bs0[128 * 64];
  __shared__ bf16 As1[128 * 64], Bs1[128 * 64];
  const bf16 *A, *Bt; bf16* C;
  switch (blockIdx.z) {
    case 0: A = qbf; Bt = WtQ; C = Qb; break;
    case 1: A = kvbf; Bt = WtK; C = Kb; break;
    default: A = kvbf; Bt = WtV; C = Vb; break;
  }
  gemm128_body<false>(A, Bt, nullptr, C, As0, Bs0, As1, Bs1);
}

__global__ __launch_bounds__(256, 2) void gemm_out(const bf16* __restrict__ A,
                                                   const bf16* __restrict__ Wt,
                                                   float* __restrict__ C) {
  __shared__ bf16 As0[128 * 64], Bs0[128 * 64];
  __shared__ bf16 As1[128 * 64], Bs1[128 * 64];
  gemm128_body<true>(A, Wt, C, nullptr, As0, Bs0, As1, Bs1);
}

// ---------------------------------------------------------------------------
// MFMA flash attention HYBRID (r0 staging + r2 in-register P):
//  * K AND V double-buffered in LDS via register prefetch one chunk ahead
//    (r0's proven latency-hiding discipline; no just-in-time global chain).
//  * 32x32x16 MFMAs, swapped operands: S^T = K(A) . Q^T(B); lane holds a
//    full P row-slice -> exp/mask/pack fully in-register (cvt_pk + permlane),
//    NO Ps LDS round-trip, NO msk01/acc_l MFMAs.
//  * mask via per-chunk 64-bit __ballot; softmax denom = VALU lsum +
//    shfl_xor(32) at the end.
//  * PV: O^T = V^T(A) . P^T(B) with V^T from Vt[d][n] LDS.
// Block = (b,h,128 Q rows), 4 waves x 32 q-rows, BN=64. LDS 33.4 KB,
// grid 512 (2 blocks/CU). All layouts verified correct in r2 (passed).
// ---------------------------------------------------------------------------
__global__ __launch_bounds__(256) void attn_mfma(const bf16* __restrict__ Qb,
                                                 const bf16* __restrict__ Kb,
                                                 const bf16* __restrict__ Vb,
                                                 const int* __restrict__ maskp,
                                                 bf16* __restrict__ Ob) {
  __shared__ bf16 Ks[2][64 * 64];   // XOR-swizzled, unpadded (16 KB)
  __shared__ bf16 Vt[2][64][68];    // [d][n] (17.4 KB)

  const int blk = blockIdx.x;
  const int h = blk & 15;
  const int b = (blk >> 4) & 1;
  const int qb = blk >> 5;  // 0..15, 128-row Q tile
  const int t = threadIdx.x;
  const int wave = t >> 6, lane = t & 63;
  const int l31 = lane & 31, hi = lane >> 5;

  // K staging map: row kr (0..63), 16-elem quarter kq
  const int kr = t >> 2, kq = t & 3;
  const bf16* gK = Kb + (size_t)(b * SEQ + kr) * DMODEL + h * 64 + kq * 16;
  const int s0 = (kq * 2) ^ (kr & 7), s1 = (kq * 2 + 1) ^ (kr & 7);
  // V staging map: tokens nv,nv+1 x 8 d per thread
  const int nv = (t & 31) * 2, dc = (t >> 5) * 8;
  const bf16* gV = Vb + (size_t)(b * SEQ + nv) * DMODEL + h * 64 + dc;
  const int* gM = maskp + b * SEQ;

  // ---- stage chunk 0 into buffer 0 ----
  {
    bf16x8 k0 = *(const bf16x8*)(gK);
    bf16x8 k1 = *(const bf16x8*)(gK + 8);
    *(bf16x8*)&Ks[0][kr * 64 + s0 * 8] = k0;
    *(bf16x8*)&Ks[0][kr * 64 + s1 * 8] = k1;
    bf16x8 v0 = *(const bf16x8*)(gV);
    bf16x8 v1 = *(const bf16x8*)(gV + DMODEL);
    union U { bf16x8 v; uint32_t dw[4]; } a, c;
    a.v = v0; c.v = v1;
#pragma unroll
    for (int d2 = 0; d2 < 4; ++d2) {
      *(uint32_t*)&Vt[0][dc + 2 * d2 + 0][nv] = __builtin_amdgcn_perm(c.dw[d2], a.dw[d2], 0x05040100u);
      *(uint32_t*)&Vt[0][dc + 2 * d2 + 1][nv] = __builtin_amdgcn_perm(c.dw[d2], a.dw[d2], 0x07060302u);
    }
  }
  int mcur = gM[lane];

  // Q as B-operand fragments: lane holds Q[q=l31][d = ks*16 + hi*8 + j]
  bf16x8 qf[4];
#pragma unroll
  for (int ks = 0; ks < 4; ++ks) {
    const bf16* g = Qb + (size_t)(b * SEQ + qb * 128 + wave * 32 + l31) * DMODEL +
                    h * 64 + ks * 16 + hi * 8;
    qf[ks] = *(const bf16x8*)g;
  }

  f32x16 o0 = {}, o1 = {};
  float lsum = 0.f;

  __syncthreads();  // buffer 0 ready

  for (int it = 0; it < SEQ / 64; ++it) {
    const int p = it & 1;
    const bool more = (it + 1) < SEQ / 64;

    // ---- issue next-chunk K/V/mask global loads (LDS-written at bottom) ----
    bf16x8 kreg0, kreg1, vreg0, vreg1;
    int mnext = 0;
    if (more) {
      const int nn = (it + 1) * 64;
      const bf16* gK2 = gK + (size_t)nn * DMODEL;
      const bf16* gV2 = gV + (size_t)nn * DMODEL;
      kreg0 = *(const bf16x8*)(gK2);
      kreg1 = *(const bf16x8*)(gK2 + 8);
      vreg0 = *(const bf16x8*)(gV2);
      vreg1 = *(const bf16x8*)(gV2 + DMODEL);
      mnext = gM[nn + lane];
    }

    // ---- S^T = K . Q^T, K A-frags from LDS (prefetched last chunk) ----
    f32x16 s0v = {}, s1v = {};
#pragma unroll
    for (int ks = 0; ks < 4; ++ks) {
      const int c = ks * 2 + hi;  // 8-elem chunk index within row
      const int r0 = l31;
      const int r1 = 32 + l31;
      bf16x8 ka0 = *(const bf16x8*)&Ks[p][r0 * 64 + (c ^ (r0 & 7)) * 8];
      bf16x8 ka1 = *(const bf16x8*)&Ks[p][r1 * 64 + (c ^ (r1 & 7)) * 8];
      s0v = __builtin_amdgcn_mfma_f32_32x32x16_bf16(ka0, qf[ks], s0v, 0, 0, 0);
      s1v = __builtin_amdgcn_mfma_f32_32x32x16_bf16(ka1, qf[ks], s1v, 0, 0, 0);
    }

    // ---- mask bitmask for this chunk (bit k = 1 means keep) ----
    const unsigned long long mb = __ballot(mcur == 0);

    // ---- exp + mask + l-sum + in-register P->bf16 B-frags + PV ----
#pragma unroll
    for (int kt = 0; kt < 2; ++kt) {
      const f32x16 sv = kt ? s1v : s0v;
      const uint32_t ml = (uint32_t)(mb >> (kt * 32 + 4 * hi));
      float pm[16];
#pragma unroll
      for (int r = 0; r < 16; ++r) {
        const int bitc = (r & 3) + 8 * (r >> 2);
        float pex = __builtin_amdgcn_exp2f(sv[r] * C1f + C2f);
        pm[r] = ((ml >> bitc) & 1u) ? pex : 0.f;
        lsum += pm[r];
      }
      uint32_t w01 = cvtpk_bf16(pm[0], pm[1]),  w23 = cvtpk_bf16(pm[2], pm[3]);
      uint32_t w45 = cvtpk_bf16(pm[4], pm[5]),  w67 = cvtpk_bf16(pm[6], pm[7]);
      uint32_t w89 = cvtpk_bf16(pm[8], pm[9]),  wab = cvtpk_bf16(pm[10], pm[11]);
      uint32_t wcd = cvtpk_bf16(pm[12], pm[13]), wef = cvtpk_bf16(pm[14], pm[15]);
      pl32swap(w01, w45);
      pl32swap(w23, w67);
      pl32swap(w89, wcd);
      pl32swap(wab, wef);
      union BF { uint32_t u[4]; bf16x8 v; } f0, f1;
      f0.u[0] = w01; f0.u[1] = w23; f0.u[2] = w45; f0.u[3] = w67;
      f1.u[0] = w89; f1.u[1] = wab; f1.u[2] = wcd; f1.u[3] = wef;
      {
        bf16x8 va00 = *(const bf16x8*)&Vt[p][0 + l31][(kt * 2 + 0) * 16 + hi * 8];
        bf16x8 va01 = *(const bf16x8*)&Vt[p][0 + l31][(kt * 2 + 1) * 16 + hi * 8];
        o0 = __builtin_amdgcn_mfma_f32_32x32x16_bf16(va00, f0.v, o0, 0, 0, 0);
        o0 = __builtin_amdgcn_mfma_f32_32x32x16_bf16(va01, f1.v, o0, 0, 0, 0);
        bf16x8 va10 = *(const bf16x8*)&Vt[p][32 + l31][(kt * 2 + 0) * 16 + hi * 8];
        bf16x8 va11 = *(const bf16x8*)&Vt[p][32 + l31][(kt * 2 + 1) * 16 + hi * 8];
        o1 = __builtin_amdgcn_mfma_f32_32x32x16_bf16(va10, f0.v, o1, 0, 0, 0);
        o1 = __builtin_amdgcn_mfma_f32_32x32x16_bf16(va11, f1.v, o1, 0, 0, 0);
      }
    }

    // ---- write staged chunk into buffer 1-p ----
    if (more) {
      const int q = 1 - p;
      *(bf16x8*)&Ks[q][kr * 64 + s0 * 8] = kreg0;
      *(bf16x8*)&Ks[q][kr * 64 + s1 * 8] = kreg1;
      union U { bf16x8 v; uint32_t dw[4]; } a, c;
      a.v = vreg0; c.v = vreg1;
#pragma unroll
      for (int d2 = 0; d2 < 4; ++d2) {
        *(uint32_t*)&Vt[q][dc + 2 * d2 + 0][nv] = __builtin_amdgcn_perm(c.dw[d2], a.dw[d2], 0x05040100u);
        *(uint32_t*)&Vt[q][dc + 2 * d2 + 1][nv] = __builtin_amdgcn_perm(c.dw[d2], a.dw[d2], 0x07060302u);
      }
    }
    mcur = mnext;
    __syncthreads();  // buffer 1-p written, buffer p reads complete
  }

  // ---- epilogue: l = own half + partner half (lane^32); normalize, store ----
  const float lt = lsum + __shfl_xor(lsum, 32);
  const float inv = 1.f / lt;
  bf16* gO = Ob + (size_t)(b * SEQ + qb * 128 + wave * 32 + l31) * DMODEL + h * 64;
#pragma unroll
  for (int g = 0; g < 4; ++g) {
    uint2 st0, st1;
    st0.x = cvtpk_bf16(o0[4 * g + 0] * inv, o0[4 * g + 1] * inv);
    st0.y = cvtpk_bf16(o0[4 * g + 2] * inv, o0[4 * g + 3] * inv);
    st1.x = cvtpk_bf16(o1[4 * g + 0] * inv, o1[4 * g + 1] * inv);
    st1.y = cvtpk_bf16(o1[4 * g + 2] * inv, o1[4 * g + 3] * inv);
    *(uint2*)(gO + 8 * g + 4 * hi) = st0;
    *(uint2*)(gO + 32 + 8 * g + 4 * hi) = st1;
  }
}

// ---------------------------------------------------------------------------
extern "C" void kernel_launch(void* const* d_in, const int* in_sizes, int n_in,
                              void* d_out, int out_size, void* d_ws, size_t ws_size,
                              hipStream_t stream) {
  (void)in_sizes; (void)n_in; (void)out_size; (void)ws_size;
  const float* query = (const float*)d_in[0];
  const float* key_value = (const float*)d_in[1];
  const int* mask = (const int*)d_in[2];
  const float* W_Q = (const float*)d_in[3];
  const float* W_K = (const float*)d_in[4];
  const float* W_V = (const float*)d_in[5];
  const float* W_O = (const float*)d_in[6];
  float* out = (float*)d_out;

  const size_t TOK = (size_t)BB * SEQ;  // 4096
  const size_t TE = TOK * DMODEL;       // 4,194,304 elems
  char* w = (char*)d_ws;
  bf16* qbf = (bf16*)w;   w += TE * 2;
  bf16* kvbf = (bf16*)w;  w += TE * 2;
  bf16* WtQ = (bf16*)w;   w += (size_t)DMODEL * DMODEL * 2;
  bf16* WtK = (bf16*)w;   w += (size_t)DMODEL * DMODEL * 2;
  bf16* WtV = (bf16*)w;   w += (size_t)DMODEL * DMODEL * 2;
  bf16* WtO = (bf16*)w;   w += (size_t)DMODEL * DMODEL * 2;
  bf16* Qbuf = (bf16*)w;  w += TE * 2;
  bf16* Kbuf = (bf16*)w;  w += TE * 2;
  bf16* Vbuf = (bf16*)w;  w += TE * 2;
  bf16* Obuf = (bf16*)w;  w += TE * 2;

  prep<<<5120, 256, 0, stream>>>(query, key_value, qbf, kvbf,
                                 W_Q, W_K, W_V, W_O, WtQ, WtK, WtV, WtO);

  gemm_qkv<<<dim3(DMODEL / 128, TOK / 128, 3), 256, 0, stream>>>(qbf, kvbf, WtQ, WtK, WtV,
                                                                 Qbuf, Kbuf, Vbuf);

  attn_mfma<<<BB * NHH * (SEQ / 128), 256, 0, stream>>>(Qbuf, Kbuf, Vbuf, mask, Obuf);

  gemm_out<<<dim3(DMODEL / 128, TOK / 128), 256, 0, stream>>>(Obuf, WtO, out);
}

// Round 6
// 203.314 us; speedup vs baseline: 1.2146x; 1.0454x over previous
//
#include <hip/hip_runtime.h>
#include <math.h>

#define BB 2
#define SEQ 2048
#define DMODEL 1024
#define NHH 16
#define DHH 64

typedef __bf16 bf16;
typedef __attribute__((ext_vector_type(8))) __bf16 bf16x8;
typedef __attribute__((ext_vector_type(4))) float f32x4;
typedef __attribute__((ext_vector_type(16))) float f32x16;

// p = exp2(s*C1 + C2) = exp(0.125*s - 4)   [static-max softmax, 0.125*|s| <~ 2.5]
#define C1f 0.18033688011112042f
#define C2f -5.770780163555854f

__device__ __forceinline__ uint32_t cvtpk_bf16(float lo, float hi) {
  uint32_t r;
  asm("v_cvt_pk_bf16_f32 %0, %1, %2" : "=v"(r) : "v"(lo), "v"(hi));
  return r;
}
__device__ __forceinline__ void pl32swap(uint32_t& a, uint32_t& b) {
  asm("v_permlane32_swap_b32 %0, %1" : "+v"(a), "+v"(b));
}

// async global -> LDS, 16B per lane. LDS dest: wave-uniform base + lane*16.
__device__ __forceinline__ void gl_lds16(const bf16* g, bf16* l) {
  __builtin_amdgcn_global_load_lds(
      (const __attribute__((address_space(1))) void*)g,
      (__attribute__((address_space(3))) void*)l, 16, 0, 0);
}

// ---------------------------------------------------------------------------
// PREP (fused): blocks [0,1024) transpose+convert the 4 weight matrices;
// blocks [1024,5120) convert the two activations.
// ---------------------------------------------------------------------------
__global__ __launch_bounds__(256) void prep(const float* __restrict__ query,
                                            const float* __restrict__ key_value,
                                            bf16* __restrict__ qbf,
                                            bf16* __restrict__ kvbf,
                                            const float* __restrict__ W0, const float* __restrict__ W1,
                                            const float* __restrict__ W2, const float* __restrict__ W3,
                                            bf16* __restrict__ O0, bf16* __restrict__ O1,
                                            bf16* __restrict__ O2, bf16* __restrict__ O3) {
  __shared__ bf16 T[64][72];
  const int bid = blockIdx.x;
  const int t = threadIdx.x;
  if (bid >= 1024) {
    const int bidc = bid - 1024;
    const float* in = (bidc >> 11) ? key_value : query;
    bf16* out = (bidc >> 11) ? kvbf : qbf;
    const int i = (bidc & 2047) * 256 + t;
    const float4* p = (const float4*)in + 2 * (size_t)i;
    float4 a = p[0], b = p[1];
    bf16x8 v;
    v[0] = (bf16)a.x; v[1] = (bf16)a.y; v[2] = (bf16)a.z; v[3] = (bf16)a.w;
    v[4] = (bf16)b.x; v[5] = (bf16)b.y; v[6] = (bf16)b.z; v[7] = (bf16)b.w;
    *((bf16x8*)out + i) = v;
    return;
  }
  const float* W; bf16* O;
  switch (bid >> 8) {
    case 0: W = W0; O = O0; break;
    case 1: W = W1; O = O1; break;
    case 2: W = W2; O = O2; break;
    default: W = W3; O = O3; break;
  }
  const int n0 = (bid & 15) * 64, k0 = ((bid >> 4) & 15) * 64;
  {
    int k = t >> 2, ns = (t & 3) * 16;
    const float* g = W + (size_t)(k0 + k) * DMODEL + n0 + ns;
#pragma unroll
    for (int q = 0; q < 4; ++q) {
      float4 f = *(const float4*)(g + 4 * q);
      T[ns + 4 * q + 0][k] = (bf16)f.x;
      T[ns + 4 * q + 1][k] = (bf16)f.y;
      T[ns + 4 * q + 2][k] = (bf16)f.z;
      T[ns + 4 * q + 3][k] = (bf16)f.w;
    }
  }
  __syncthreads();
  {
    int n = t >> 2, ks = (t & 3) * 16;
    bf16x8 a = *(const bf16x8*)&T[n][ks];
    bf16x8 b = *(const bf16x8*)&T[n][ks + 8];
    bf16* o = O + (size_t)(n0 + n) * DMODEL + k0 + ks;
    *(bf16x8*)o = a;
    *(bf16x8*)(o + 8) = b;
  }
}

// ---------------------------------------------------------------------------
// bf16 MFMA GEMM, 128x128 tile, BK=64, double-buffered global_load_lds
// staging (r4/r5 structure, unchanged).
// ---------------------------------------------------------------------------
template <bool F32OUT>
__device__ __forceinline__ void gemm128_body(const bf16* __restrict__ A,
                                             const bf16* __restrict__ Bt,
                                             float* __restrict__ Cf,
                                             bf16* __restrict__ Cb,
                                             bf16* As0, bf16* Bs0,
                                             bf16* As1, bf16* Bs1) {
  const int t = threadIdx.x;
  const int lane = t & 63, wave = t >> 6;
  const int l15 = lane & 15, quad = lane >> 4;
  const int bm = blockIdx.y * 128, bn = blockIdx.x * 128;
  const int wr = wave >> 1, wc = wave & 1;

  const int srow = wave * 32 + (lane >> 3);  // + j*8
  const int sc = lane & 7;
  const int ca = sc ^ ((lane >> 3) & 7);  // pre-swizzled global chunk
  const bf16* gA = A + (size_t)(bm + srow) * DMODEL + ca * 8;
  const bf16* gB = Bt + (size_t)(bn + srow) * DMODEL + ca * 8;
  const int lo = wave * 32 * 64;

  f32x4 acc[4][4] = {};

#define STAGE(KT, AS, BS)                                                \
  {                                                                      \
    const int kk = (KT) * 64;                                            \
    _Pragma("unroll") for (int j = 0; j < 4; ++j) {                      \
      gl_lds16(gA + (size_t)(j * 8) * DMODEL + kk, (AS) + lo + j * 512); \
      gl_lds16(gB + (size_t)(j * 8) * DMODEL + kk, (BS) + lo + j * 512); \
    }                                                                    \
  }

#define COMPUTE(AS, BS)                                                \
  {                                                                    \
    _Pragma("unroll") for (int ks = 0; ks < 2; ++ks) {                 \
      bf16x8 af[4], bfr[4];                                            \
      _Pragma("unroll") for (int mt = 0; mt < 4; ++mt) {               \
        int row = wr * 64 + mt * 16 + l15;                             \
        int s = (ks * 4 + quad) ^ (row & 7);                           \
        af[mt] = *(const bf16x8*)&(AS)[row * 64 + s * 8];              \
      }                                                                \
      _Pragma("unroll") for (int nt = 0; nt < 4; ++nt) {               \
        int row = wc * 64 + nt * 16 + l15;                             \
        int s = (ks * 4 + quad) ^ (row & 7);                           \
        bfr[nt] = *(const bf16x8*)&(BS)[row * 64 + s * 8];             \
      }                                                                \
      _Pragma("unroll") for (int mt = 0; mt < 4; ++mt)                 \
          _Pragma("unroll") for (int nt = 0; nt < 4; ++nt)             \
              acc[mt][nt] = __builtin_amdgcn_mfma_f32_16x16x32_bf16(   \
                  af[mt], bfr[nt], acc[mt][nt], 0, 0, 0);              \
    }                                                                  \
  }

  STAGE(0, As0, Bs0);
  __syncthreads();

  for (int kt = 0; kt < DMODEL / 64; kt += 2) {
    if (kt + 1 < DMODEL / 64) STAGE(kt + 1, As1, Bs1);
    COMPUTE(As0, Bs0);
    __syncthreads();
    if (kt + 2 < DMODEL / 64) STAGE(kt + 2, As0, Bs0);
    COMPUTE(As1, Bs1);
    __syncthreads();
  }
#undef STAGE
#undef COMPUTE

#pragma unroll
  for (int mt = 0; mt < 4; ++mt)
#pragma unroll
    for (int nt = 0; nt < 4; ++nt)
#pragma unroll
      for (int r = 0; r < 4; ++r) {
        int row = bm + wr * 64 + mt * 16 + quad * 4 + r;
        int col = bn + wc * 64 + nt * 16 + l15;
        if (F32OUT) Cf[(size_t)row * DMODEL + col] = acc[mt][nt][r];
        else Cb[(size_t)row * DMODEL + col] = (bf16)acc[mt][nt][r];
      }
}

__global__ __launch_bounds__(256, 2) void gemm_qkv(const bf16* __restrict__ qbf,
                                                   const bf16* __restrict__ kvbf,
                                                   const bf16* __restrict__ WtQ,
                                                   const bf16* __restrict__ WtK,
                                                   const bf16* __restrict__ WtV,
                                                   bf16* __restrict__ Qb,
                                                   bf16* __restrict__ Kb,
                                                   bf16* __restrict__ Vb) {
  __shared__ bf16 As0[128 * 64], Bs0[128 * 64];
  __shared__ bf16 As1[128 * 64], Bs1[128 * 64];
  const bf16 *A, *Bt; bf16* C;
  switch (blockIdx.z) {
    case 0: A = qbf; Bt = WtQ; C = Qb; break;
    case 1: A = kvbf; Bt = WtK; C = Kb; break;
    default: A = kvbf; Bt = WtV; C = Vb; break;
  }
  gemm128_body<false>(A, Bt, nullptr, C, As0, Bs0, As1, Bs1);
}

__global__ __launch_bounds__(256, 2) void gemm_out(const bf16* __restrict__ A,
                                                   const bf16* __restrict__ Wt,
                                                   float* __restrict__ C) {
  __shared__ bf16 As0[128 * 64], Bs0[128 * 64];
  __shared__ bf16 As1[128 * 64], Bs1[128 * 64];
  gemm128_body<true>(A, Wt, C, nullptr, As0, Bs0, As1, Bs1);
}

// ---------------------------------------------------------------------------
// MFMA flash attention, K-SPLIT version (r5 in-register-P + 2x TLP):
//  * 8 waves / 512 threads per block. Waves 0-3 (group 0) process KV tokens
//    [0,1024); waves 4-7 (group 1) process [1024,2048) -- SAME 128 q-rows.
//    Static-max softmax => partials are purely additive (no rescale):
//    O = oA + oB, l = lA + lB. Doubles waves/SIMD 2 -> 4 for the same
//    per-wave per-chunk work (r5's shape exactly).
//  * Ks now PADDED [64][68] like Vt, XOR swizzle dropped: the 32-row x
//    8-slot XOR read was a structural 4-way bank conflict (2.1M in r5);
//    pad-68 gives rows stride 34 banks -> worst 2-way (free).
//  * Each group double-buffers its own K/V (LDS 69.6 KB, 2 blocks/CU).
//  * Epilogue: l partials via 1KB LDS scratch; group 0 dumps o into the
//    freed Ks region (pad-33 f32 rows, conflict-free); group 1 combines,
//    normalizes, stores.
// ---------------------------------------------------------------------------
__global__ __launch_bounds__(512, 4) void attn_mfma(const bf16* __restrict__ Qb,
                                                    const bf16* __restrict__ Kb,
                                                    const bf16* __restrict__ Vb,
                                                    const int* __restrict__ maskp,
                                                    bf16* __restrict__ Ob) {
  __shared__ bf16 Ks[2][2][64][68];  // [group][dbuf][token][d]   34.8 KB
  __shared__ bf16 Vt[2][2][64][68];  // [group][dbuf][d][token]   34.8 KB

  const int blk = blockIdx.x;
  const int h = blk & 15;
  const int b = (blk >> 4) & 1;
  const int qb = blk >> 5;  // 0..15, 128-row Q tile
  const int t = threadIdx.x;
  const int wave = t >> 6, lane = t & 63;
  const int grp = wave >> 2;   // KV half
  const int w4 = wave & 3;     // q-subtile
  const int l31 = lane & 31, hi = lane >> 5;
  const int tl = t & 255;      // group-local thread id

  // K staging map (group-local): row kr (0..63), 16-elem quarter kq
  const int kr = tl >> 2, kq = tl & 3;
  const bf16* gK = Kb + (size_t)(b * SEQ + grp * 1024 + kr) * DMODEL + h * 64 + kq * 16;
  // V staging map: tokens nv,nv+1 x 8 d per thread
  const int nv = (tl & 31) * 2, dc = (tl >> 5) * 8;
  const bf16* gV = Vb + (size_t)(b * SEQ + grp * 1024 + nv) * DMODEL + h * 64 + dc;
  const int* gM = maskp + b * SEQ + grp * 1024;

  // ---- stage chunk 0 into buffer 0 ----
  {
    bf16x8 k0 = *(const bf16x8*)(gK);
    bf16x8 k1 = *(const bf16x8*)(gK + 8);
    *(bf16x8*)&Ks[grp][0][kr][kq * 16] = k0;
    *(bf16x8*)&Ks[grp][0][kr][kq * 16 + 8] = k1;
    bf16x8 v0 = *(const bf16x8*)(gV);
    bf16x8 v1 = *(const bf16x8*)(gV + DMODEL);
    union U { bf16x8 v; uint32_t dw[4]; } a, c;
    a.v = v0; c.v = v1;
#pragma unroll
    for (int d2 = 0; d2 < 4; ++d2) {
      *(uint32_t*)&Vt[grp][0][dc + 2 * d2 + 0][nv] = __builtin_amdgcn_perm(c.dw[d2], a.dw[d2], 0x05040100u);
      *(uint32_t*)&Vt[grp][0][dc + 2 * d2 + 1][nv] = __builtin_amdgcn_perm(c.dw[d2], a.dw[d2], 0x07060302u);
    }
  }
  int mcur = gM[lane];

  // Q as B-operand fragments: lane holds Q[q=l31][d = ks*16 + hi*8 + j]
  bf16x8 qf[4];
#pragma unroll
  for (int ks = 0; ks < 4; ++ks) {
    const bf16* g = Qb + (size_t)(b * SEQ + qb * 128 + w4 * 32 + l31) * DMODEL +
                    h * 64 + ks * 16 + hi * 8;
    qf[ks] = *(const bf16x8*)g;
  }

  f32x16 o0 = {}, o1 = {};
  float lsum = 0.f;

  __syncthreads();  // buffer 0 ready

  for (int it = 0; it < 16; ++it) {
    const int p = it & 1;
    const bool more = (it + 1) < 16;

    // ---- issue next-chunk K/V/mask global loads (LDS-written at bottom) ----
    bf16x8 kreg0, kreg1, vreg0, vreg1;
    int mnext = 0;
    if (more) {
      const int nn = (it + 1) * 64;
      const bf16* gK2 = gK + (size_t)nn * DMODEL;
      const bf16* gV2 = gV + (size_t)nn * DMODEL;
      kreg0 = *(const bf16x8*)(gK2);
      kreg1 = *(const bf16x8*)(gK2 + 8);
      vreg0 = *(const bf16x8*)(gV2);
      vreg1 = *(const bf16x8*)(gV2 + DMODEL);
      mnext = gM[nn + lane];
    }

    // ---- S^T = K . Q^T, K A-frags from padded LDS (no swizzle) ----
    f32x16 s0v = {}, s1v = {};
#pragma unroll
    for (int ks = 0; ks < 4; ++ks) {
      const int c = (ks * 2 + hi) * 8;
      bf16x8 ka0 = *(const bf16x8*)&Ks[grp][p][l31][c];
      bf16x8 ka1 = *(const bf16x8*)&Ks[grp][p][32 + l31][c];
      s0v = __builtin_amdgcn_mfma_f32_32x32x16_bf16(ka0, qf[ks], s0v, 0, 0, 0);
      s1v = __builtin_amdgcn_mfma_f32_32x32x16_bf16(ka1, qf[ks], s1v, 0, 0, 0);
    }

    // ---- mask bitmask for this chunk (bit k = 1 means keep) ----
    const unsigned long long mb = __ballot(mcur == 0);

    // ---- exp + mask + l-sum + in-register P->bf16 B-frags + PV ----
#pragma unroll
    for (int kt = 0; kt < 2; ++kt) {
      const f32x16 sv = kt ? s1v : s0v;
      const uint32_t ml = (uint32_t)(mb >> (kt * 32 + 4 * hi));
      float pm[16];
#pragma unroll
      for (int r = 0; r < 16; ++r) {
        const int bitc = (r & 3) + 8 * (r >> 2);
        float pex = __builtin_amdgcn_exp2f(sv[r] * C1f + C2f);
        pm[r] = ((ml >> bitc) & 1u) ? pex : 0.f;
        lsum += pm[r];
      }
      uint32_t w01 = cvtpk_bf16(pm[0], pm[1]),  w23 = cvtpk_bf16(pm[2], pm[3]);
      uint32_t w45 = cvtpk_bf16(pm[4], pm[5]),  w67 = cvtpk_bf16(pm[6], pm[7]);
      uint32_t w89 = cvtpk_bf16(pm[8], pm[9]),  wab = cvtpk_bf16(pm[10], pm[11]);
      uint32_t wcd = cvtpk_bf16(pm[12], pm[13]), wef = cvtpk_bf16(pm[14], pm[15]);
      pl32swap(w01, w45);
      pl32swap(w23, w67);
      pl32swap(w89, wcd);
      pl32swap(wab, wef);
      union BF { uint32_t u[4]; bf16x8 v; } f0, f1;
      f0.u[0] = w01; f0.u[1] = w23; f0.u[2] = w45; f0.u[3] = w67;
      f1.u[0] = w89; f1.u[1] = wab; f1.u[2] = wcd; f1.u[3] = wef;
      {
        bf16x8 va00 = *(const bf16x8*)&Vt[grp][p][0 + l31][(kt * 2 + 0) * 16 + hi * 8];
        bf16x8 va01 = *(const bf16x8*)&Vt[grp][p][0 + l31][(kt * 2 + 1) * 16 + hi * 8];
        o0 = __builtin_amdgcn_mfma_f32_32x32x16_bf16(va00, f0.v, o0, 0, 0, 0);
        o0 = __builtin_amdgcn_mfma_f32_32x32x16_bf16(va01, f1.v, o0, 0, 0, 0);
        bf16x8 va10 = *(const bf16x8*)&Vt[grp][p][32 + l31][(kt * 2 + 0) * 16 + hi * 8];
        bf16x8 va11 = *(const bf16x8*)&Vt[grp][p][32 + l31][(kt * 2 + 1) * 16 + hi * 8];
        o1 = __builtin_amdgcn_mfma_f32_32x32x16_bf16(va10, f0.v, o1, 0, 0, 0);
        o1 = __builtin_amdgcn_mfma_f32_32x32x16_bf16(va11, f1.v, o1, 0, 0, 0);
      }
    }

    // ---- write staged chunk into buffer 1-p ----
    if (more) {
      const int q = 1 - p;
      *(bf16x8*)&Ks[grp][q][kr][kq * 16] = kreg0;
      *(bf16x8*)&Ks[grp][q][kr][kq * 16 + 8] = kreg1;
      union U { bf16x8 v; uint32_t dw[4]; } a, c;
      a.v = vreg0; c.v = vreg1;
#pragma unroll
      for (int d2 = 0; d2 < 4; ++d2) {
        *(uint32_t*)&Vt[grp][q][dc + 2 * d2 + 0][nv] = __builtin_amdgcn_perm(c.dw[d2], a.dw[d2], 0x05040100u);
        *(uint32_t*)&Vt[grp][q][dc + 2 * d2 + 1][nv] = __builtin_amdgcn_perm(c.dw[d2], a.dw[d2], 0x07060302u);
      }
    }
    mcur = mnext;
    __syncthreads();  // buffer 1-p written, buffer p reads complete
  }

  // ---- epilogue: combine the two KV-half partials, normalize, store ----
  // l partial for this wave's q-rows (sum over its KV half):
  const float ltp = lsum + __shfl_xor(lsum, 32);

  // scratch overlays the (now dead) Ks region: scL[8][32] f32, then
  // scO[4][64][33] f32 (pad-33 rows => lane-distinct banks). 34,816 B total.
  float* sc = (float*)&Ks[0][0][0][0];
  float* scO = sc + 256;

  if (hi == 0) sc[wave * 32 + l31] = ltp;
  if (grp == 0) {
    float* dst = scO + ((size_t)(w4 * 64 + lane)) * 33;
#pragma unroll
    for (int r = 0; r < 16; ++r) {
      dst[r] = o0[r];
      dst[16 + r] = o1[r];
    }
  }
  __syncthreads();
  if (grp == 1) {
    const float ltot = sc[w4 * 32 + l31] + sc[(4 + w4) * 32 + l31];
    const float inv = 1.f / ltot;
    const float* src = scO + ((size_t)(w4 * 64 + lane)) * 33;
#pragma unroll
    for (int r = 0; r < 16; ++r) {
      o0[r] += src[r];
      o1[r] += src[16 + r];
    }
    bf16* gO = Ob + (size_t)(b * SEQ + qb * 128 + w4 * 32 + l31) * DMODEL + h * 64;
#pragma unroll
    for (int g = 0; g < 4; ++g) {
      uint2 st0, st1;
      st0.x = cvtpk_bf16(o0[4 * g + 0] * inv, o0[4 * g + 1] * inv);
      st0.y = cvtpk_bf16(o0[4 * g + 2] * inv, o0[4 * g + 3] * inv);
      st1.x = cvtpk_bf16(o1[4 * g + 0] * inv, o1[4 * g + 1] * inv);
      st1.y = cvtpk_bf16(o1[4 * g + 2] * inv, o1[4 * g + 3] * inv);
      *(uint2*)(gO + 8 * g + 4 * hi) = st0;
      *(uint2*)(gO + 32 + 8 * g + 4 * hi) = st1;
    }
  }
}

// ---------------------------------------------------------------------------
extern "C" void kernel_launch(void* const* d_in, const int* in_sizes, int n_in,
                              void* d_out, int out_size, void* d_ws, size_t ws_size,
                              hipStream_t stream) {
  (void)in_sizes; (void)n_in; (void)out_size; (void)ws_size;
  const float* query = (const float*)d_in[0];
  const float* key_value = (const float*)d_in[1];
  const int* mask = (const int*)d_in[2];
  const float* W_Q = (const float*)d_in[3];
  const float* W_K = (const float*)d_in[4];
  const float* W_V = (const float*)d_in[5];
  const float* W_O = (const float*)d_in[6];
  float* out = (float*)d_out;

  const size_t TOK = (size_t)BB * SEQ;  // 4096
  const size_t TE = TOK * DMODEL;       // 4,194,304 elems
  char* w = (char*)d_ws;
  bf16* qbf = (bf16*)w;   w += TE * 2;
  bf16* kvbf = (bf16*)w;  w += TE * 2;
  bf16* WtQ = (bf16*)w;   w += (size_t)DMODEL * DMODEL * 2;
  bf16* WtK = (bf16*)w;   w += (size_t)DMODEL * DMODEL * 2;
  bf16* WtV = (bf16*)w;   w += (size_t)DMODEL * DMODEL * 2;
  bf16* WtO = (bf16*)w;   w += (size_t)DMODEL * DMODEL * 2;
  bf16* Qbuf = (bf16*)w;  w += TE * 2;
  bf16* Kbuf = (bf16*)w;  w += TE * 2;
  bf16* Vbuf = (bf16*)w;  w += TE * 2;
  bf16* Obuf = (bf16*)w;  w += TE * 2;

  prep<<<5120, 256, 0, stream>>>(query, key_value, qbf, kvbf,
                                 W_Q, W_K, W_V, W_O, WtQ, WtK, WtV, WtO);

  gemm_qkv<<<dim3(DMODEL / 128, TOK / 128, 3), 256, 0, stream>>>(qbf, kvbf, WtQ, WtK, WtV,
                                                                 Qbuf, Kbuf, Vbuf);

  attn_mfma<<<BB * NHH * (SEQ / 128), 512, 0, stream>>>(Qbuf, Kbuf, Vbuf, mask, Obuf);

  gemm_out<<<dim3(DMODEL / 128, TOK / 128), 256, 0, stream>>>(Obuf, WtO, out);
}

// Round 8
// 202.667 us; speedup vs baseline: 1.2184x; 1.0032x over previous
//
#include <hip/hip_runtime.h>
#include <math.h>

#define BB 2
#define SEQ 2048
#define DMODEL 1024
#define NHH 16
#define DHH 64

typedef __bf16 bf16;
typedef __attribute__((ext_vector_type(8))) __bf16 bf16x8;
typedef __attribute__((ext_vector_type(4))) float f32x4;
typedef __attribute__((ext_vector_type(16))) float f32x16;

// p = exp2(s*C1 + C2) = exp(0.125*s - 4)   [static-max softmax, 0.125*|s| <~ 2.5]
#define C1f 0.18033688011112042f
#define C2f -5.770780163555854f

__device__ __forceinline__ uint32_t cvtpk_bf16(float lo, float hi) {
  uint32_t r;
  asm("v_cvt_pk_bf16_f32 %0, %1, %2" : "=v"(r) : "v"(lo), "v"(hi));
  return r;
}
__device__ __forceinline__ void pl32swap(uint32_t& a, uint32_t& b) {
  asm("v_permlane32_swap_b32 %0, %1" : "+v"(a), "+v"(b));
}

// async global -> LDS, 16B per lane. LDS dest: wave-uniform base + lane*16.
__device__ __forceinline__ void gl_lds16(const bf16* g, bf16* l) {
  __builtin_amdgcn_global_load_lds(
      (const __attribute__((address_space(1))) void*)g,
      (__attribute__((address_space(3))) void*)l, 16, 0, 0);
}

// ---------------------------------------------------------------------------
// PREP (fused): blocks [0,1024) transpose+convert the 4 weight matrices;
// blocks [1024,5120) convert the two activations.
// ---------------------------------------------------------------------------
__global__ __launch_bounds__(256) void prep(const float* __restrict__ query,
                                            const float* __restrict__ key_value,
                                            bf16* __restrict__ qbf,
                                            bf16* __restrict__ kvbf,
                                            const float* __restrict__ W0, const float* __restrict__ W1,
                                            const float* __restrict__ W2, const float* __restrict__ W3,
                                            bf16* __restrict__ O0, bf16* __restrict__ O1,
                                            bf16* __restrict__ O2, bf16* __restrict__ O3) {
  __shared__ bf16 T[64][72];
  const int bid = blockIdx.x;
  const int t = threadIdx.x;
  if (bid >= 1024) {
    const int bidc = bid - 1024;
    const float* in = (bidc >> 11) ? key_value : query;
    bf16* out = (bidc >> 11) ? kvbf : qbf;
    const int i = (bidc & 2047) * 256 + t;
    const float4* p = (const float4*)in + 2 * (size_t)i;
    float4 a = p[0], b = p[1];
    bf16x8 v;
    v[0] = (bf16)a.x; v[1] = (bf16)a.y; v[2] = (bf16)a.z; v[3] = (bf16)a.w;
    v[4] = (bf16)b.x; v[5] = (bf16)b.y; v[6] = (bf16)b.z; v[7] = (bf16)b.w;
    *((bf16x8*)out + i) = v;
    return;
  }
  const float* W; bf16* O;
  switch (bid >> 8) {
    case 0: W = W0; O = O0; break;
    case 1: W = W1; O = O1; break;
    case 2: W = W2; O = O2; break;
    default: W = W3; O = O3; break;
  }
  const int n0 = (bid & 15) * 64, k0 = ((bid >> 4) & 15) * 64;
  {
    int k = t >> 2, ns = (t & 3) * 16;
    const float* g = W + (size_t)(k0 + k) * DMODEL + n0 + ns;
#pragma unroll
    for (int q = 0; q < 4; ++q) {
      float4 f = *(const float4*)(g + 4 * q);
      T[ns + 4 * q + 0][k] = (bf16)f.x;
      T[ns + 4 * q + 1][k] = (bf16)f.y;
      T[ns + 4 * q + 2][k] = (bf16)f.z;
      T[ns + 4 * q + 3][k] = (bf16)f.w;
    }
  }
  __syncthreads();
  {
    int n = t >> 2, ks = (t & 3) * 16;
    bf16x8 a = *(const bf16x8*)&T[n][ks];
    bf16x8 b = *(const bf16x8*)&T[n][ks + 8];
    bf16* o = O + (size_t)(n0 + n) * DMODEL + k0 + ks;
    *(bf16x8*)o = a;
    *(bf16x8*)(o + 8) = b;
  }
}

// ---------------------------------------------------------------------------
// bf16 MFMA GEMM, 128(m) x 32*NT(n) tile, BK=64, double-buffered
// global_load_lds staging. NT=4: 128x128 (gemm_qkv, grid 768; identical
// mapping to the r6 hardcoded body). NT=2: 128x64 (gemm_out, grid 512 ->
// ALL CUs busy; the 128x128 grid (8,32)=256 blocks left half the chip idle).
// ---------------------------------------------------------------------------
template <bool F32OUT, int NT>
__device__ __forceinline__ void gemm128_body(const bf16* __restrict__ A,
                                             const bf16* __restrict__ Bt,
                                             float* __restrict__ Cf,
                                             bf16* __restrict__ Cb,
                                             bf16* As0, bf16* Bs0,
                                             bf16* As1, bf16* Bs1) {
  const int t = threadIdx.x;
  const int lane = t & 63, wave = t >> 6;
  const int l15 = lane & 15, quad = lane >> 4;
  const int bm = blockIdx.y * 128, bn = blockIdx.x * (32 * NT);
  const int wr = wave >> 1, wc = wave & 1;

  const int sr8 = lane >> 3;                // 0..7
  const int sc = lane & 7;
  const int ca = sc ^ (sr8 & 7);            // pre-swizzled global chunk
  const bf16* gA = A + (size_t)(bm + wave * 32 + sr8) * DMODEL + ca * 8;
  const bf16* gB = Bt + (size_t)(bn + wave * (8 * NT) + sr8) * DMODEL + ca * 8;
  const int loA = wave * 32 * 64;
  const int loB = wave * (8 * NT) * 64;

  f32x4 acc[4][NT] = {};

#define STAGE(KT, AS, BS)                                                 \
  {                                                                       \
    const int kk = (KT) * 64;                                             \
    _Pragma("unroll") for (int j = 0; j < 4; ++j)                         \
        gl_lds16(gA + (size_t)(j * 8) * DMODEL + kk, (AS) + loA + j * 512); \
    _Pragma("unroll") for (int j = 0; j < NT; ++j)                        \
        gl_lds16(gB + (size_t)(j * 8) * DMODEL + kk, (BS) + loB + j * 512); \
  }

#define COMPUTE(AS, BS)                                                \
  {                                                                    \
    _Pragma("unroll") for (int ks = 0; ks < 2; ++ks) {                 \
      bf16x8 af[4], bfr[NT];                                           \
      _Pragma("unroll") for (int mt = 0; mt < 4; ++mt) {               \
        int row = wr * 64 + mt * 16 + l15;                             \
        int s = (ks * 4 + quad) ^ (row & 7);                           \
        af[mt] = *(const bf16x8*)&(AS)[row * 64 + s * 8];              \
      }                                                                \
      _Pragma("unroll") for (int nt = 0; nt < NT; ++nt) {              \
        int row = wc * (16 * NT) + nt * 16 + l15;                      \
        int s = (ks * 4 + quad) ^ (row & 7);                           \
        bfr[nt] = *(const bf16x8*)&(BS)[row * 64 + s * 8];             \
      }                                                                \
      _Pragma("unroll") for (int mt = 0; mt < 4; ++mt)                 \
          _Pragma("unroll") for (int nt = 0; nt < NT; ++nt)            \
              acc[mt][nt] = __builtin_amdgcn_mfma_f32_16x16x32_bf16(   \
                  af[mt], bfr[nt], acc[mt][nt], 0, 0, 0);              \
    }                                                                  \
  }

  STAGE(0, As0, Bs0);
  __syncthreads();

  for (int kt = 0; kt < DMODEL / 64; kt += 2) {
    if (kt + 1 < DMODEL / 64) STAGE(kt + 1, As1, Bs1);
    COMPUTE(As0, Bs0);
    __syncthreads();
    if (kt + 2 < DMODEL / 64) STAGE(kt + 2, As0, Bs0);
    COMPUTE(As1, Bs1);
    __syncthreads();
  }
#undef STAGE
#undef COMPUTE

#pragma unroll
  for (int mt = 0; mt < 4; ++mt)
#pragma unroll
    for (int nt = 0; nt < NT; ++nt)
#pragma unroll
      for (int r = 0; r < 4; ++r) {
        int row = bm + wr * 64 + mt * 16 + quad * 4 + r;
        int col = bn + wc * (16 * NT) + nt * 16 + l15;
        if (F32OUT) Cf[(size_t)row * DMODEL + col] = acc[mt][nt][r];
        else Cb[(size_t)row * DMODEL + col] = (bf16)acc[mt][nt][r];
      }
}

__global__ __launch_bounds__(256, 2) void gemm_qkv(const bf16* __restrict__ qbf,
                                                   const bf16* __restrict__ kvbf,
                                                   const bf16* __restrict__ WtQ,
                                                   const bf16* __restrict__ WtK,
                                                   const bf16* __restrict__ WtV,
                                                   bf16* __restrict__ Qb,
                                                   bf16* __restrict__ Kb,
                                                   bf16* __restrict__ Vb) {
  __shared__ bf16 As0[128 * 64], Bs0[128 * 64];
  __shared__ bf16 As1[128 * 64], Bs1[128 * 64];
  const bf16 *A, *Bt; bf16* C;
  switch (blockIdx.z) {
    case 0: A = qbf; Bt = WtQ; C = Qb; break;
    case 1: A = kvbf; Bt = WtK; C = Kb; break;
    default: A = kvbf; Bt = WtV; C = Vb; break;
  }
  gemm128_body<false, 4>(A, Bt, nullptr, C, As0, Bs0, As1, Bs1);
}

__global__ __launch_bounds__(256, 3) void gemm_out(const bf16* __restrict__ A,
                                                   const bf16* __restrict__ Wt,
                                                   float* __restrict__ C) {
  __shared__ bf16 As0[128 * 64], Bs0[64 * 64];
  __shared__ bf16 As1[128 * 64], Bs1[64 * 64];
  gemm128_body<true, 2>(A, Wt, C, nullptr, As0, Bs0, As1, Bs1);
}

// ---------------------------------------------------------------------------
// MFMA flash attention, K-SPLIT version — EXACT r6 kernel (passed, 59.6 us):
//  * 8 waves / 512 threads per block. Waves 0-3 (group 0) process KV tokens
//    [0,1024); waves 4-7 (group 1) process [1024,2048) -- SAME 128 q-rows.
//    Static-max softmax => partials purely additive: O = oA+oB, l = lA+lB.
//  * In-register P (swapped 32x32 QK^T, cvt_pk + permlane32_swap), ballot
//    mask, VALU lsum. Padded LDS [64][68] (no swizzle, worst 2-way = free).
//  * Each group double-buffers its own K/V (LDS 69.6 KB, 2 blocks/CU).
// r7's mask-MFMA/V-zeroing variant FAILED (absmax 2e5) — do not reintroduce
// without a verified layout derivation.
// ---------------------------------------------------------------------------
__global__ __launch_bounds__(512, 4) void attn_mfma(const bf16* __restrict__ Qb,
                                                    const bf16* __restrict__ Kb,
                                                    const bf16* __restrict__ Vb,
                                                    const int* __restrict__ maskp,
                                                    bf16* __restrict__ Ob) {
  __shared__ bf16 Ks[2][2][64][68];  // [group][dbuf][token][d]   34.8 KB
  __shared__ bf16 Vt[2][2][64][68];  // [group][dbuf][d][token]   34.8 KB

  const int blk = blockIdx.x;
  const int h = blk & 15;
  const int b = (blk >> 4) & 1;
  const int qb = blk >> 5;  // 0..15, 128-row Q tile
  const int t = threadIdx.x;
  const int wave = t >> 6, lane = t & 63;
  const int grp = wave >> 2;   // KV half
  const int w4 = wave & 3;     // q-subtile
  const int l31 = lane & 31, hi = lane >> 5;
  const int tl = t & 255;      // group-local thread id

  // K staging map (group-local): row kr (0..63), 16-elem quarter kq
  const int kr = tl >> 2, kq = tl & 3;
  const bf16* gK = Kb + (size_t)(b * SEQ + grp * 1024 + kr) * DMODEL + h * 64 + kq * 16;
  // V staging map: tokens nv,nv+1 x 8 d per thread
  const int nv = (tl & 31) * 2, dc = (tl >> 5) * 8;
  const bf16* gV = Vb + (size_t)(b * SEQ + grp * 1024 + nv) * DMODEL + h * 64 + dc;
  const int* gM = maskp + b * SEQ + grp * 1024;

  // ---- stage chunk 0 into buffer 0 ----
  {
    bf16x8 k0 = *(const bf16x8*)(gK);
    bf16x8 k1 = *(const bf16x8*)(gK + 8);
    *(bf16x8*)&Ks[grp][0][kr][kq * 16] = k0;
    *(bf16x8*)&Ks[grp][0][kr][kq * 16 + 8] = k1;
    bf16x8 v0 = *(const bf16x8*)(gV);
    bf16x8 v1 = *(const bf16x8*)(gV + DMODEL);
    union U { bf16x8 v; uint32_t dw[4]; } a, c;
    a.v = v0; c.v = v1;
#pragma unroll
    for (int d2 = 0; d2 < 4; ++d2) {
      *(uint32_t*)&Vt[grp][0][dc + 2 * d2 + 0][nv] = __builtin_amdgcn_perm(c.dw[d2], a.dw[d2], 0x05040100u);
      *(uint32_t*)&Vt[grp][0][dc + 2 * d2 + 1][nv] = __builtin_amdgcn_perm(c.dw[d2], a.dw[d2], 0x07060302u);
    }
  }
  int mcur = gM[lane];

  // Q as B-operand fragments: lane holds Q[q=l31][d = ks*16 + hi*8 + j]
  bf16x8 qf[4];
#pragma unroll
  for (int ks = 0; ks < 4; ++ks) {
    const bf16* g = Qb + (size_t)(b * SEQ + qb * 128 + w4 * 32 + l31) * DMODEL +
                    h * 64 + ks * 16 + hi * 8;
    qf[ks] = *(const bf16x8*)g;
  }

  f32x16 o0 = {}, o1 = {};
  float lsum = 0.f;

  __syncthreads();  // buffer 0 ready

  for (int it = 0; it < 16; ++it) {
    const int p = it & 1;
    const bool more = (it + 1) < 16;

    // ---- issue next-chunk K/V/mask global loads (LDS-written at bottom) ----
    bf16x8 kreg0, kreg1, vreg0, vreg1;
    int mnext = 0;
    if (more) {
      const int nn = (it + 1) * 64;
      const bf16* gK2 = gK + (size_t)nn * DMODEL;
      const bf16* gV2 = gV + (size_t)nn * DMODEL;
      kreg0 = *(const bf16x8*)(gK2);
      kreg1 = *(const bf16x8*)(gK2 + 8);
      vreg0 = *(const bf16x8*)(gV2);
      vreg1 = *(const bf16x8*)(gV2 + DMODEL);
      mnext = gM[nn + lane];
    }

    // ---- S^T = K . Q^T, K A-frags from padded LDS (no swizzle) ----
    f32x16 s0v = {}, s1v = {};
#pragma unroll
    for (int ks = 0; ks < 4; ++ks) {
      const int c = (ks * 2 + hi) * 8;
      bf16x8 ka0 = *(const bf16x8*)&Ks[grp][p][l31][c];
      bf16x8 ka1 = *(const bf16x8*)&Ks[grp][p][32 + l31][c];
      s0v = __builtin_amdgcn_mfma_f32_32x32x16_bf16(ka0, qf[ks], s0v, 0, 0, 0);
      s1v = __builtin_amdgcn_mfma_f32_32x32x16_bf16(ka1, qf[ks], s1v, 0, 0, 0);
    }

    // ---- mask bitmask for this chunk (bit k = 1 means keep) ----
    const unsigned long long mb = __ballot(mcur == 0);

    // ---- exp + mask + l-sum + in-register P->bf16 B-frags + PV ----
#pragma unroll
    for (int kt = 0; kt < 2; ++kt) {
      const f32x16 sv = kt ? s1v : s0v;
      const uint32_t ml = (uint32_t)(mb >> (kt * 32 + 4 * hi));
      float pm[16];
#pragma unroll
      for (int r = 0; r < 16; ++r) {
        const int bitc = (r & 3) + 8 * (r >> 2);
        float pex = __builtin_amdgcn_exp2f(sv[r] * C1f + C2f);
        pm[r] = ((ml >> bitc) & 1u) ? pex : 0.f;
        lsum += pm[r];
      }
      uint32_t w01 = cvtpk_bf16(pm[0], pm[1]),  w23 = cvtpk_bf16(pm[2], pm[3]);
      uint32_t w45 = cvtpk_bf16(pm[4], pm[5]),  w67 = cvtpk_bf16(pm[6], pm[7]);
      uint32_t w89 = cvtpk_bf16(pm[8], pm[9]),  wab = cvtpk_bf16(pm[10], pm[11]);
      uint32_t wcd = cvtpk_bf16(pm[12], pm[13]), wef = cvtpk_bf16(pm[14], pm[15]);
      pl32swap(w01, w45);
      pl32swap(w23, w67);
      pl32swap(w89, wcd);
      pl32swap(wab, wef);
      union BF { uint32_t u[4]; bf16x8 v; } f0, f1;
      f0.u[0] = w01; f0.u[1] = w23; f0.u[2] = w45; f0.u[3] = w67;
      f1.u[0] = w89; f1.u[1] = wab; f1.u[2] = wcd; f1.u[3] = wef;
      {
        bf16x8 va00 = *(const bf16x8*)&Vt[grp][p][0 + l31][(kt * 2 + 0) * 16 + hi * 8];
        bf16x8 va01 = *(const bf16x8*)&Vt[grp][p][0 + l31][(kt * 2 + 1) * 16 + hi * 8];
        o0 = __builtin_amdgcn_mfma_f32_32x32x16_bf16(va00, f0.v, o0, 0, 0, 0);
        o0 = __builtin_amdgcn_mfma_f32_32x32x16_bf16(va01, f1.v, o0, 0, 0, 0);
        bf16x8 va10 = *(const bf16x8*)&Vt[grp][p][32 + l31][(kt * 2 + 0) * 16 + hi * 8];
        bf16x8 va11 = *(const bf16x8*)&Vt[grp][p][32 + l31][(kt * 2 + 1) * 16 + hi * 8];
        o1 = __builtin_amdgcn_mfma_f32_32x32x16_bf16(va10, f0.v, o1, 0, 0, 0);
        o1 = __builtin_amdgcn_mfma_f32_32x32x16_bf16(va11, f1.v, o1, 0, 0, 0);
      }
    }

    // ---- write staged chunk into buffer 1-p ----
    if (more) {
      const int q = 1 - p;
      *(bf16x8*)&Ks[grp][q][kr][kq * 16] = kreg0;
      *(bf16x8*)&Ks[grp][q][kr][kq * 16 + 8] = kreg1;
      union U { bf16x8 v; uint32_t dw[4]; } a, c;
      a.v = vreg0; c.v = vreg1;
#pragma unroll
      for (int d2 = 0; d2 < 4; ++d2) {
        *(uint32_t*)&Vt[grp][q][dc + 2 * d2 + 0][nv] = __builtin_amdgcn_perm(c.dw[d2], a.dw[d2], 0x05040100u);
        *(uint32_t*)&Vt[grp][q][dc + 2 * d2 + 1][nv] = __builtin_amdgcn_perm(c.dw[d2], a.dw[d2], 0x07060302u);
      }
    }
    mcur = mnext;
    __syncthreads();  // buffer 1-p written, buffer p reads complete
  }

  // ---- epilogue: combine the two KV-half partials, normalize, store ----
  const float ltp = lsum + __shfl_xor(lsum, 32);

  // scratch overlays the (now dead) Ks region: scL[8][32] f32, then
  // scO[4][64][33] f32 (pad-33 rows => lane-distinct banks). 34,816 B total.
  float* sc = (float*)&Ks[0][0][0][0];
  float* scO = sc + 256;

  if (hi == 0) sc[wave * 32 + l31] = ltp;
  if (grp == 0) {
    float* dst = scO + ((size_t)(w4 * 64 + lane)) * 33;
#pragma unroll
    for (int r = 0; r < 16; ++r) {
      dst[r] = o0[r];
      dst[16 + r] = o1[r];
    }
  }
  __syncthreads();
  if (grp == 1) {
    const float ltot = sc[w4 * 32 + l31] + sc[(4 + w4) * 32 + l31];
    const float inv = 1.f / ltot;
    const float* src = scO + ((size_t)(w4 * 64 + lane)) * 33;
#pragma unroll
    for (int r = 0; r < 16; ++r) {
      o0[r] += src[r];
      o1[r] += src[16 + r];
    }
    bf16* gO = Ob + (size_t)(b * SEQ + qb * 128 + w4 * 32 + l31) * DMODEL + h * 64;
#pragma unroll
    for (int g = 0; g < 4; ++g) {
      uint2 st0, st1;
      st0.x = cvtpk_bf16(o0[4 * g + 0] * inv, o0[4 * g + 1] * inv);
      st0.y = cvtpk_bf16(o0[4 * g + 2] * inv, o0[4 * g + 3] * inv);
      st1.x = cvtpk_bf16(o1[4 * g + 0] * inv, o1[4 * g + 1] * inv);
      st1.y = cvtpk_bf16(o1[4 * g + 2] * inv, o1[4 * g + 3] * inv);
      *(uint2*)(gO + 8 * g + 4 * hi) = st0;
      *(uint2*)(gO + 32 + 8 * g + 4 * hi) = st1;
    }
  }
}

// ---------------------------------------------------------------------------
extern "C" void kernel_launch(void* const* d_in, const int* in_sizes, int n_in,
                              void* d_out, int out_size, void* d_ws, size_t ws_size,
                              hipStream_t stream) {
  (void)in_sizes; (void)n_in; (void)out_size; (void)ws_size;
  const float* query = (const float*)d_in[0];
  const float* key_value = (const float*)d_in[1];
  const int* mask = (const int*)d_in[2];
  const float* W_Q = (const float*)d_in[3];
  const float* W_K = (const float*)d_in[4];
  const float* W_V = (const float*)d_in[5];
  const float* W_O = (const float*)d_in[6];
  float* out = (float*)d_out;

  const size_t TOK = (size_t)BB * SEQ;  // 4096
  const size_t TE = TOK * DMODEL;       // 4,194,304 elems
  char* w = (char*)d_ws;
  bf16* qbf = (bf16*)w;   w += TE * 2;
  bf16* kvbf = (bf16*)w;  w += TE * 2;
  bf16* WtQ = (bf16*)w;   w += (size_t)DMODEL * DMODEL * 2;
  bf16* WtK = (bf16*)w;   w += (size_t)DMODEL * DMODEL * 2;
  bf16* WtV = (bf16*)w;   w += (size_t)DMODEL * DMODEL * 2;
  bf16* WtO = (bf16*)w;   w += (size_t)DMODEL * DMODEL * 2;
  bf16* Qbuf = (bf16*)w;  w += TE * 2;
  bf16* Kbuf = (bf16*)w;  w += TE * 2;
  bf16* Vbuf = (bf16*)w;  w += TE * 2;
  bf16* Obuf = (bf16*)w;  w += TE * 2;

  prep<<<5120, 256, 0, stream>>>(query, key_value, qbf, kvbf,
                                 W_Q, W_K, W_V, W_O, WtQ, WtK, WtV, WtO);

  gemm_qkv<<<dim3(DMODEL / 128, TOK / 128, 3), 256, 0, stream>>>(qbf, kvbf, WtQ, WtK, WtV,
                                                                 Qbuf, Kbuf, Vbuf);

  attn_mfma<<<BB * NHH * (SEQ / 128), 512, 0, stream>>>(Qbuf, Kbuf, Vbuf, mask, Obuf);

  gemm_out<<<dim3(DMODEL / 64, TOK / 128), 256, 0, stream>>>(Obuf, WtO, out);
}

// Round 9
// 198.517 us; speedup vs baseline: 1.2439x; 1.0209x over previous
//
#include <hip/hip_runtime.h>
#include <math.h>

#define BB 2
#define SEQ 2048
#define DMODEL 1024
#define NHH 16
#define DHH 64

typedef __bf16 bf16;
typedef __attribute__((ext_vector_type(8))) __bf16 bf16x8;
typedef __attribute__((ext_vector_type(4))) float f32x4;
typedef __attribute__((ext_vector_type(16))) float f32x16;

// p = exp2(s*C1 + C2) = exp(0.125*s - 4)   [static-max softmax, 0.125*|s| <~ 2.5]
#define C1f 0.18033688011112042f
#define C2f -5.770780163555854f

__device__ __forceinline__ uint32_t cvtpk_bf16(float lo, float hi) {
  uint32_t r;
  asm("v_cvt_pk_bf16_f32 %0, %1, %2" : "=v"(r) : "v"(lo), "v"(hi));
  return r;
}
__device__ __forceinline__ void pl32swap(uint32_t& a, uint32_t& b) {
  asm("v_permlane32_swap_b32 %0, %1" : "+v"(a), "+v"(b));
}

// async global -> LDS, 16B per lane. LDS dest: wave-uniform base + lane*16.
__device__ __forceinline__ void gl_lds16(const bf16* g, bf16* l) {
  __builtin_amdgcn_global_load_lds(
      (const __attribute__((address_space(1))) void*)g,
      (__attribute__((address_space(3))) void*)l, 16, 0, 0);
}

// ---------------------------------------------------------------------------
// PREP (fused): blocks [0,1024) transpose+convert the 4 weight matrices;
// blocks [1024,5120) convert the two activations.
// ---------------------------------------------------------------------------
__global__ __launch_bounds__(256) void prep(const float* __restrict__ query,
                                            const float* __restrict__ key_value,
                                            bf16* __restrict__ qbf,
                                            bf16* __restrict__ kvbf,
                                            const float* __restrict__ W0, const float* __restrict__ W1,
                                            const float* __restrict__ W2, const float* __restrict__ W3,
                                            bf16* __restrict__ O0, bf16* __restrict__ O1,
                                            bf16* __restrict__ O2, bf16* __restrict__ O3) {
  __shared__ bf16 T[64][72];
  const int bid = blockIdx.x;
  const int t = threadIdx.x;
  if (bid >= 1024) {
    const int bidc = bid - 1024;
    const float* in = (bidc >> 11) ? key_value : query;
    bf16* out = (bidc >> 11) ? kvbf : qbf;
    const int i = (bidc & 2047) * 256 + t;
    const float4* p = (const float4*)in + 2 * (size_t)i;
    float4 a = p[0], b = p[1];
    bf16x8 v;
    v[0] = (bf16)a.x; v[1] = (bf16)a.y; v[2] = (bf16)a.z; v[3] = (bf16)a.w;
    v[4] = (bf16)b.x; v[5] = (bf16)b.y; v[6] = (bf16)b.z; v[7] = (bf16)b.w;
    *((bf16x8*)out + i) = v;
    return;
  }
  const float* W; bf16* O;
  switch (bid >> 8) {
    case 0: W = W0; O = O0; break;
    case 1: W = W1; O = O1; break;
    case 2: W = W2; O = O2; break;
    default: W = W3; O = O3; break;
  }
  const int n0 = (bid & 15) * 64, k0 = ((bid >> 4) & 15) * 64;
  {
    int k = t >> 2, ns = (t & 3) * 16;
    const float* g = W + (size_t)(k0 + k) * DMODEL + n0 + ns;
#pragma unroll
    for (int q = 0; q < 4; ++q) {
      float4 f = *(const float4*)(g + 4 * q);
      T[ns + 4 * q + 0][k] = (bf16)f.x;
      T[ns + 4 * q + 1][k] = (bf16)f.y;
      T[ns + 4 * q + 2][k] = (bf16)f.z;
      T[ns + 4 * q + 3][k] = (bf16)f.w;
    }
  }
  __syncthreads();
  {
    int n = t >> 2, ks = (t & 3) * 16;
    bf16x8 a = *(const bf16x8*)&T[n][ks];
    bf16x8 b = *(const bf16x8*)&T[n][ks + 8];
    bf16* o = O + (size_t)(n0 + n) * DMODEL + k0 + ks;
    *(bf16x8*)o = a;
    *(bf16x8*)(o + 8) = b;
  }
}

// ---------------------------------------------------------------------------
// gemm_qkv: 256(m) x 128(n) tile, BK=64, SINGLE-buffered global_load_lds
// staging (r3/r4 showed dbuf is neutral here). 512 threads, 8 waves in 4x2,
// wave = 64x64 (4x4 frags). B-weight staging traffic HALVES vs BM=128
// (re-reads M/BM: 32 -> 16). 384 blocks, all co-resident. LDS 48 KB.
// ---------------------------------------------------------------------------
__global__ __launch_bounds__(512) void gemm_qkv(const bf16* __restrict__ qbf,
                                                const bf16* __restrict__ kvbf,
                                                const bf16* __restrict__ WtQ,
                                                const bf16* __restrict__ WtK,
                                                const bf16* __restrict__ WtV,
                                                bf16* __restrict__ Qb,
                                                bf16* __restrict__ Kb,
                                                bf16* __restrict__ Vb) {
  __shared__ bf16 As[256 * 64];  // 32 KB
  __shared__ bf16 Bs[128 * 64];  // 16 KB
  const bf16 *A, *Bt; bf16* C;
  switch (blockIdx.z) {
    case 0: A = qbf; Bt = WtQ; C = Qb; break;
    case 1: A = kvbf; Bt = WtK; C = Kb; break;
    default: A = kvbf; Bt = WtV; C = Vb; break;
  }

  const int t = threadIdx.x;
  const int lane = t & 63, wave = t >> 6;
  const int l15 = lane & 15, quad = lane >> 4;
  const int bm = blockIdx.y * 256, bn = blockIdx.x * 128;
  const int wr = wave >> 1, wc = wave & 1;  // 4x2 wave grid

  // staging map: 512 threads, each 16B/issue. row = t>>3 (0..63) + j*64.
  const int srow = t >> 3;
  const int sc = t & 7;
  const int ca = sc ^ (srow & 7);  // pre-swizzled global chunk (j*64 keeps row&7)
  const bf16* gA = A + (size_t)(bm + srow) * DMODEL + ca * 8;
  const bf16* gB = Bt + (size_t)(bn + srow) * DMODEL + ca * 8;
  // per-wave linear LDS base: bytes = wave*1024 + lane*16 (elems: wave*512+...)
  const int lo = wave * 512;

  f32x4 acc[4][4] = {};

  for (int kt = 0; kt < DMODEL / 64; ++kt) {
    const int kk = kt * 64;
    // A: 4 issues x 64 rows; B: 2 issues x 64 rows
#pragma unroll
    for (int j = 0; j < 4; ++j)
      gl_lds16(gA + (size_t)(j * 64) * DMODEL + kk, As + lo + j * 4096);
#pragma unroll
    for (int j = 0; j < 2; ++j)
      gl_lds16(gB + (size_t)(j * 64) * DMODEL + kk, Bs + lo + j * 4096);
    __syncthreads();  // drains vmcnt: LDS tiles ready
#pragma unroll
    for (int ks = 0; ks < 2; ++ks) {
      bf16x8 af[4], bfr[4];
#pragma unroll
      for (int mt = 0; mt < 4; ++mt) {
        int row = wr * 64 + mt * 16 + l15;
        int s = (ks * 4 + quad) ^ (row & 7);
        af[mt] = *(const bf16x8*)&As[row * 64 + s * 8];
      }
#pragma unroll
      for (int nt = 0; nt < 4; ++nt) {
        int row = wc * 64 + nt * 16 + l15;
        int s = (ks * 4 + quad) ^ (row & 7);
        bfr[nt] = *(const bf16x8*)&Bs[row * 64 + s * 8];
      }
#pragma unroll
      for (int mt = 0; mt < 4; ++mt)
#pragma unroll
        for (int nt = 0; nt < 4; ++nt)
          acc[mt][nt] = __builtin_amdgcn_mfma_f32_16x16x32_bf16(af[mt], bfr[nt], acc[mt][nt], 0, 0, 0);
    }
    __syncthreads();  // frag reads done before next stage overwrites
  }

#pragma unroll
  for (int mt = 0; mt < 4; ++mt)
#pragma unroll
    for (int nt = 0; nt < 4; ++nt)
#pragma unroll
      for (int r = 0; r < 4; ++r) {
        int row = bm + wr * 64 + mt * 16 + quad * 4 + r;
        int col = bn + wc * 64 + nt * 16 + l15;
        C[(size_t)row * DMODEL + col] = (bf16)acc[mt][nt][r];
      }
}

// ---------------------------------------------------------------------------
// gemm_out: r8-exact 128(m) x 64(n) tile, BK=64, double-buffered
// global_load_lds staging; grid 512 -> all CUs busy.
// ---------------------------------------------------------------------------
__global__ __launch_bounds__(256, 3) void gemm_out(const bf16* __restrict__ A,
                                                   const bf16* __restrict__ Wt,
                                                   float* __restrict__ C) {
  __shared__ bf16 As0[128 * 64], Bs0[64 * 64];
  __shared__ bf16 As1[128 * 64], Bs1[64 * 64];
  const int NT = 2;

  const int t = threadIdx.x;
  const int lane = t & 63, wave = t >> 6;
  const int l15 = lane & 15, quad = lane >> 4;
  const int bm = blockIdx.y * 128, bn = blockIdx.x * (32 * NT);
  const int wr = wave >> 1, wc = wave & 1;

  const int sr8 = lane >> 3;
  const int sc = lane & 7;
  const int ca = sc ^ (sr8 & 7);
  const bf16* gA = A + (size_t)(bm + wave * 32 + sr8) * DMODEL + ca * 8;
  const bf16* gB = Wt + (size_t)(bn + wave * (8 * NT) + sr8) * DMODEL + ca * 8;
  const int loA = wave * 32 * 64;
  const int loB = wave * (8 * NT) * 64;

  f32x4 acc[4][NT] = {};

#define STAGE(KT, AS, BS)                                                 \
  {                                                                       \
    const int kk = (KT) * 64;                                             \
    _Pragma("unroll") for (int j = 0; j < 4; ++j)                         \
        gl_lds16(gA + (size_t)(j * 8) * DMODEL + kk, (AS) + loA + j * 512); \
    _Pragma("unroll") for (int j = 0; j < NT; ++j)                        \
        gl_lds16(gB + (size_t)(j * 8) * DMODEL + kk, (BS) + loB + j * 512); \
  }

#define COMPUTE(AS, BS)                                                \
  {                                                                    \
    _Pragma("unroll") for (int ks = 0; ks < 2; ++ks) {                 \
      bf16x8 af[4], bfr[NT];                                           \
      _Pragma("unroll") for (int mt = 0; mt < 4; ++mt) {               \
        int row = wr * 64 + mt * 16 + l15;                             \
        int s = (ks * 4 + quad) ^ (row & 7);                           \
        af[mt] = *(const bf16x8*)&(AS)[row * 64 + s * 8];              \
      }                                                                \
      _Pragma("unroll") for (int nt = 0; nt < NT; ++nt) {              \
        int row = wc * (16 * NT) + nt * 16 + l15;                      \
        int s = (ks * 4 + quad) ^ (row & 7);                           \
        bfr[nt] = *(const bf16x8*)&(BS)[row * 64 + s * 8];             \
      }                                                                \
      _Pragma("unroll") for (int mt = 0; mt < 4; ++mt)                 \
          _Pragma("unroll") for (int nt = 0; nt < NT; ++nt)            \
              acc[mt][nt] = __builtin_amdgcn_mfma_f32_16x16x32_bf16(   \
                  af[mt], bfr[nt], acc[mt][nt], 0, 0, 0);              \
    }                                                                  \
  }

  STAGE(0, As0, Bs0);
  __syncthreads();

  for (int kt = 0; kt < DMODEL / 64; kt += 2) {
    if (kt + 1 < DMODEL / 64) STAGE(kt + 1, As1, Bs1);
    COMPUTE(As0, Bs0);
    __syncthreads();
    if (kt + 2 < DMODEL / 64) STAGE(kt + 2, As0, Bs0);
    COMPUTE(As1, Bs1);
    __syncthreads();
  }
#undef STAGE
#undef COMPUTE

#pragma unroll
  for (int mt = 0; mt < 4; ++mt)
#pragma unroll
    for (int nt = 0; nt < NT; ++nt)
#pragma unroll
      for (int r = 0; r < 4; ++r) {
        int row = bm + wr * 64 + mt * 16 + quad * 4 + r;
        int col = bn + wc * (16 * NT) + nt * 16 + l15;
        C[(size_t)row * DMODEL + col] = acc[mt][nt][r];
      }
}

// ---------------------------------------------------------------------------
// MFMA flash attention, K-SPLIT version — EXACT r6/r8 kernel (58.6 us):
// 8 waves; groups of 4 split the KV range; in-register P (swapped 32x32
// QK^T, cvt_pk + permlane32_swap); ballot mask + VALU lsum; padded LDS.
// ---------------------------------------------------------------------------
__global__ __launch_bounds__(512, 4) void attn_mfma(const bf16* __restrict__ Qb,
                                                    const bf16* __restrict__ Kb,
                                                    const bf16* __restrict__ Vb,
                                                    const int* __restrict__ maskp,
                                                    bf16* __restrict__ Ob) {
  __shared__ bf16 Ks[2][2][64][68];  // [group][dbuf][token][d]   34.8 KB
  __shared__ bf16 Vt[2][2][64][68];  // [group][dbuf][d][token]   34.8 KB

  const int blk = blockIdx.x;
  const int h = blk & 15;
  const int b = (blk >> 4) & 1;
  const int qb = blk >> 5;  // 0..15, 128-row Q tile
  const int t = threadIdx.x;
  const int wave = t >> 6, lane = t & 63;
  const int grp = wave >> 2;   // KV half
  const int w4 = wave & 3;     // q-subtile
  const int l31 = lane & 31, hi = lane >> 5;
  const int tl = t & 255;      // group-local thread id

  const int kr = tl >> 2, kq = tl & 3;
  const bf16* gK = Kb + (size_t)(b * SEQ + grp * 1024 + kr) * DMODEL + h * 64 + kq * 16;
  const int nv = (tl & 31) * 2, dc = (tl >> 5) * 8;
  const bf16* gV = Vb + (size_t)(b * SEQ + grp * 1024 + nv) * DMODEL + h * 64 + dc;
  const int* gM = maskp + b * SEQ + grp * 1024;

  // ---- stage chunk 0 into buffer 0 ----
  {
    bf16x8 k0 = *(const bf16x8*)(gK);
    bf16x8 k1 = *(const bf16x8*)(gK + 8);
    *(bf16x8*)&Ks[grp][0][kr][kq * 16] = k0;
    *(bf16x8*)&Ks[grp][0][kr][kq * 16 + 8] = k1;
    bf16x8 v0 = *(const bf16x8*)(gV);
    bf16x8 v1 = *(const bf16x8*)(gV + DMODEL);
    union U { bf16x8 v; uint32_t dw[4]; } a, c;
    a.v = v0; c.v = v1;
#pragma unroll
    for (int d2 = 0; d2 < 4; ++d2) {
      *(uint32_t*)&Vt[grp][0][dc + 2 * d2 + 0][nv] = __builtin_amdgcn_perm(c.dw[d2], a.dw[d2], 0x05040100u);
      *(uint32_t*)&Vt[grp][0][dc + 2 * d2 + 1][nv] = __builtin_amdgcn_perm(c.dw[d2], a.dw[d2], 0x07060302u);
    }
  }
  int mcur = gM[lane];

  bf16x8 qf[4];
#pragma unroll
  for (int ks = 0; ks < 4; ++ks) {
    const bf16* g = Qb + (size_t)(b * SEQ + qb * 128 + w4 * 32 + l31) * DMODEL +
                    h * 64 + ks * 16 + hi * 8;
    qf[ks] = *(const bf16x8*)g;
  }

  f32x16 o0 = {}, o1 = {};
  float lsum = 0.f;

  __syncthreads();  // buffer 0 ready

  for (int it = 0; it < 16; ++it) {
    const int p = it & 1;
    const bool more = (it + 1) < 16;

    bf16x8 kreg0, kreg1, vreg0, vreg1;
    int mnext = 0;
    if (more) {
      const int nn = (it + 1) * 64;
      const bf16* gK2 = gK + (size_t)nn * DMODEL;
      const bf16* gV2 = gV + (size_t)nn * DMODEL;
      kreg0 = *(const bf16x8*)(gK2);
      kreg1 = *(const bf16x8*)(gK2 + 8);
      vreg0 = *(const bf16x8*)(gV2);
      vreg1 = *(const bf16x8*)(gV2 + DMODEL);
      mnext = gM[nn + lane];
    }

    f32x16 s0v = {}, s1v = {};
#pragma unroll
    for (int ks = 0; ks < 4; ++ks) {
      const int c = (ks * 2 + hi) * 8;
      bf16x8 ka0 = *(const bf16x8*)&Ks[grp][p][l31][c];
      bf16x8 ka1 = *(const bf16x8*)&Ks[grp][p][32 + l31][c];
      s0v = __builtin_amdgcn_mfma_f32_32x32x16_bf16(ka0, qf[ks], s0v, 0, 0, 0);
      s1v = __builtin_amdgcn_mfma_f32_32x32x16_bf16(ka1, qf[ks], s1v, 0, 0, 0);
    }

    const unsigned long long mb = __ballot(mcur == 0);

#pragma unroll
    for (int kt = 0; kt < 2; ++kt) {
      const f32x16 sv = kt ? s1v : s0v;
      const uint32_t ml = (uint32_t)(mb >> (kt * 32 + 4 * hi));
      float pm[16];
#pragma unroll
      for (int r = 0; r < 16; ++r) {
        const int bitc = (r & 3) + 8 * (r >> 2);
        float pex = __builtin_amdgcn_exp2f(sv[r] * C1f + C2f);
        pm[r] = ((ml >> bitc) & 1u) ? pex : 0.f;
        lsum += pm[r];
      }
      uint32_t w01 = cvtpk_bf16(pm[0], pm[1]),  w23 = cvtpk_bf16(pm[2], pm[3]);
      uint32_t w45 = cvtpk_bf16(pm[4], pm[5]),  w67 = cvtpk_bf16(pm[6], pm[7]);
      uint32_t w89 = cvtpk_bf16(pm[8], pm[9]),  wab = cvtpk_bf16(pm[10], pm[11]);
      uint32_t wcd = cvtpk_bf16(pm[12], pm[13]), wef = cvtpk_bf16(pm[14], pm[15]);
      pl32swap(w01, w45);
      pl32swap(w23, w67);
      pl32swap(w89, wcd);
      pl32swap(wab, wef);
      union BF { uint32_t u[4]; bf16x8 v; } f0, f1;
      f0.u[0] = w01; f0.u[1] = w23; f0.u[2] = w45; f0.u[3] = w67;
      f1.u[0] = w89; f1.u[1] = wab; f1.u[2] = wcd; f1.u[3] = wef;
      {
        bf16x8 va00 = *(const bf16x8*)&Vt[grp][p][0 + l31][(kt * 2 + 0) * 16 + hi * 8];
        bf16x8 va01 = *(const bf16x8*)&Vt[grp][p][0 + l31][(kt * 2 + 1) * 16 + hi * 8];
        o0 = __builtin_amdgcn_mfma_f32_32x32x16_bf16(va00, f0.v, o0, 0, 0, 0);
        o0 = __builtin_amdgcn_mfma_f32_32x32x16_bf16(va01, f1.v, o0, 0, 0, 0);
        bf16x8 va10 = *(const bf16x8*)&Vt[grp][p][32 + l31][(kt * 2 + 0) * 16 + hi * 8];
        bf16x8 va11 = *(const bf16x8*)&Vt[grp][p][32 + l31][(kt * 2 + 1) * 16 + hi * 8];
        o1 = __builtin_amdgcn_mfma_f32_32x32x16_bf16(va10, f0.v, o1, 0, 0, 0);
        o1 = __builtin_amdgcn_mfma_f32_32x32x16_bf16(va11, f1.v, o1, 0, 0, 0);
      }
    }

    if (more) {
      const int q = 1 - p;
      *(bf16x8*)&Ks[grp][q][kr][kq * 16] = kreg0;
      *(bf16x8*)&Ks[grp][q][kr][kq * 16 + 8] = kreg1;
      union U { bf16x8 v; uint32_t dw[4]; } a, c;
      a.v = vreg0; c.v = vreg1;
#pragma unroll
      for (int d2 = 0; d2 < 4; ++d2) {
        *(uint32_t*)&Vt[grp][q][dc + 2 * d2 + 0][nv] = __builtin_amdgcn_perm(c.dw[d2], a.dw[d2], 0x05040100u);
        *(uint32_t*)&Vt[grp][q][dc + 2 * d2 + 1][nv] = __builtin_amdgcn_perm(c.dw[d2], a.dw[d2], 0x07060302u);
      }
    }
    mcur = mnext;
    __syncthreads();  // buffer 1-p written, buffer p reads complete
  }

  // ---- epilogue: combine the two KV-half partials, normalize, store ----
  const float ltp = lsum + __shfl_xor(lsum, 32);

  float* sc = (float*)&Ks[0][0][0][0];
  float* scO = sc + 256;

  if (hi == 0) sc[wave * 32 + l31] = ltp;
  if (grp == 0) {
    float* dst = scO + ((size_t)(w4 * 64 + lane)) * 33;
#pragma unroll
    for (int r = 0; r < 16; ++r) {
      dst[r] = o0[r];
      dst[16 + r] = o1[r];
    }
  }
  __syncthreads();
  if (grp == 1) {
    const float ltot = sc[w4 * 32 + l31] + sc[(4 + w4) * 32 + l31];
    const float inv = 1.f / ltot;
    const float* src = scO + ((size_t)(w4 * 64 + lane)) * 33;
#pragma unroll
    for (int r = 0; r < 16; ++r) {
      o0[r] += src[r];
      o1[r] += src[16 + r];
    }
    bf16* gO = Ob + (size_t)(b * SEQ + qb * 128 + w4 * 32 + l31) * DMODEL + h * 64;
#pragma unroll
    for (int g = 0; g < 4; ++g) {
      uint2 st0, st1;
      st0.x = cvtpk_bf16(o0[4 * g + 0] * inv, o0[4 * g + 1] * inv);
      st0.y = cvtpk_bf16(o0[4 * g + 2] * inv, o0[4 * g + 3] * inv);
      st1.x = cvtpk_bf16(o1[4 * g + 0] * inv, o1[4 * g + 1] * inv);
      st1.y = cvtpk_bf16(o1[4 * g + 2] * inv, o1[4 * g + 3] * inv);
      *(uint2*)(gO + 8 * g + 4 * hi) = st0;
      *(uint2*)(gO + 32 + 8 * g + 4 * hi) = st1;
    }
  }
}

// ---------------------------------------------------------------------------
extern "C" void kernel_launch(void* const* d_in, const int* in_sizes, int n_in,
                              void* d_out, int out_size, void* d_ws, size_t ws_size,
                              hipStream_t stream) {
  (void)in_sizes; (void)n_in; (void)out_size; (void)ws_size;
  const float* query = (const float*)d_in[0];
  const float* key_value = (const float*)d_in[1];
  const int* mask = (const int*)d_in[2];
  const float* W_Q = (const float*)d_in[3];
  const float* W_K = (const float*)d_in[4];
  const float* W_V = (const float*)d_in[5];
  const float* W_O = (const float*)d_in[6];
  float* out = (float*)d_out;

  const size_t TOK = (size_t)BB * SEQ;  // 4096
  const size_t TE = TOK * DMODEL;       // 4,194,304 elems
  char* w = (char*)d_ws;
  bf16* qbf = (bf16*)w;   w += TE * 2;
  bf16* kvbf = (bf16*)w;  w += TE * 2;
  bf16* WtQ = (bf16*)w;   w += (size_t)DMODEL * DMODEL * 2;
  bf16* WtK = (bf16*)w;   w += (size_t)DMODEL * DMODEL * 2;
  bf16* WtV = (bf16*)w;   w += (size_t)DMODEL * DMODEL * 2;
  bf16* WtO = (bf16*)w;   w += (size_t)DMODEL * DMODEL * 2;
  bf16* Qbuf = (bf16*)w;  w += TE * 2;
  bf16* Kbuf = (bf16*)w;  w += TE * 2;
  bf16* Vbuf = (bf16*)w;  w += TE * 2;
  bf16* Obuf = (bf16*)w;  w += TE * 2;

  prep<<<5120, 256, 0, stream>>>(query, key_value, qbf, kvbf,
                                 W_Q, W_K, W_V, W_O, WtQ, WtK, WtV, WtO);

  gemm_qkv<<<dim3(DMODEL / 128, TOK / 256, 3), 512, 0, stream>>>(qbf, kvbf, WtQ, WtK, WtV,
                                                                 Qbuf, Kbuf, Vbuf);

  attn_mfma<<<BB * NHH * (SEQ / 128), 512, 0, stream>>>(Qbuf, Kbuf, Vbuf, mask, Obuf);

  gemm_out<<<dim3(DMODEL / 64, TOK / 128), 256, 0, stream>>>(Obuf, WtO, out);
}